// Round 19
// baseline (13455.481 us; speedup 1.0000x reference)
//
#include <hip/hip_runtime.h>
#include <cstddef>

// ---------------------------------------------------------------------------
// VQVAE forward. Conv v7: r16 geometry (BO=128, 256 thr, LDS 45.5 KB) with
// __launch_bounds__(256,3) -> 3 blocks/CU (136 KB LDS, VGPR cap 170 > 120
// needed, no clamp). Theory: conv is barrier-drain-bound at ~1.7 blocks/CU;
// more co-resident waves overlap the vmcnt(0)+barrier stall. FMA order
// bit-identical to r16/r18 (both passed). Decoder: fused QKV. Tail f64.
// TCN block: out = relu( relu(conv2(relu(conv1+b1))+b2) + res ).
// Workspace 256 MB.
// ---------------------------------------------------------------------------

static __device__ __forceinline__ float geluf(float x) {
  return 0.5f * x * (1.0f + erff(x * 0.70710678118654752440f));
}

// ---------------- fp32 conv: out[b][o][t] over [B][C][T], full batch ----
template<int CIN, int KSIZE, bool FROMX, bool RES, bool RELU>
__global__ __launch_bounds__(256, 3) void kconv32(
    const float* __restrict__ gin, const float* __restrict__ gw,
    const float* __restrict__ gbias, float* __restrict__ gout,
    const float* __restrict__ gres)
{
  constexpr int BT = 256, BO = 128;
  constexpr int PAD = KSIZE - 1;          // causal left pad
  constexpr int KI = (CIN < 16) ? CIN : 16;
  constexpr int JW = KI * KSIZE;
  constexpr int UW = BT + PAD;
  constexpr int UW_S = (KSIZE == 3) ? (UW + 2) : UW;   // stage through halo b128
  constexpr int RS = (UW_S - 1) + (((UW_S - 1) >> 4) << 2) + 1;  // skewed row size
  constexpr int T = 2048;
  constexpr bool SWZ = (CIN >= 16);       // swizzled weight staging (JW%4==0)
  constexpr int WSZ = (KSIZE == 3) ? 20 : 16;

  __shared__ float ins[KI][RS];
  __shared__ float wls[JW][BO];

  const int tid = threadIdx.x;
  const int tx = tid & 15, ty = tid >> 4;
  const int t0 = blockIdx.x * BT;
  const int o0 = blockIdx.y * BO;
  const int b  = blockIdx.z;

  const float* inb = gin + (FROMX ? (size_t)b * T * 7 : (size_t)b * 256 * T);

  float acc[8][16];
#pragma unroll
  for (int i = 0; i < 8; i++)
#pragma unroll
    for (int j = 0; j < 16; j++) acc[i][j] = 0.0f;

  for (int i0 = 0; i0 < CIN; i0 += KI) {
    __syncthreads();
    // stage inputs skewed: ins[ii][phys(u)] = in[i0+ii][t0-PAD+u]
    for (int f = tid; f < KI * UW_S; f += 256) {
      int ii = f / UW_S, u = f - ii * UW_S;
      int t = t0 - PAD + u;
      float v = 0.0f;
      if (t >= 0 && t < T) v = FROMX ? inb[t * 7 + (i0 + ii)]
                                     : inb[(size_t)(i0 + ii) * T + t];
      ins[ii][u + ((u >> 4) << 2)] = v;
    }
    // stage weights
    if constexpr (SWZ) {
      // float4-coalesced global read (j-fast), XOR-swizzled LDS write:
      // logical wls[j][oo] stored at [j][ ((oo>>2)^(j>>2))*4 + (oo&3) ].
#pragma unroll
      for (int r = 0; r < (JW * BO / 4 + 255) / 256; r++) {
        int f = tid + r * 256;
        int oo = f / (JW / 4);
        int jq = f - oo * (JW / 4);
        int j  = jq * 4;
        const float4 w4 = *(const float4*)&gw[(size_t)(o0 + oo) * (CIN * KSIZE)
                                              + (size_t)i0 * KSIZE + j];
        const int col = (((oo >> 2) ^ jq) << 2) | (oo & 3);
        wls[j + 0][col] = w4.x;
        wls[j + 1][col] = w4.y;
        wls[j + 2][col] = w4.z;
        wls[j + 3][col] = w4.w;
      }
    } else {
      for (int f = tid; f < JW * BO; f += 256) {
        int oo = f & (BO - 1), j = f >> 7;
        wls[j][oo] = gw[(size_t)(o0 + oo) * (CIN * KSIZE) + (size_t)i0 * KSIZE + j];
      }
    }
    __syncthreads();
#pragma unroll
    for (int ii = 0; ii < KI; ii++) {
      // thread's input window: u in [16*tx, 16*tx + WSZ); phys(16tx) = 20tx
      float w[WSZ];
      {
        const float* pr = &ins[ii][20 * tx];
        float4 v0 = *(const float4*)(pr + 0);
        float4 v1 = *(const float4*)(pr + 4);
        float4 v2 = *(const float4*)(pr + 8);
        float4 v3 = *(const float4*)(pr + 12);
        w[0]=v0.x; w[1]=v0.y; w[2]=v0.z; w[3]=v0.w;
        w[4]=v1.x; w[5]=v1.y; w[6]=v1.z; w[7]=v1.w;
        w[8]=v2.x; w[9]=v2.y; w[10]=v2.z; w[11]=v2.w;
        w[12]=v3.x; w[13]=v3.y; w[14]=v3.z; w[15]=v3.w;
        if constexpr (KSIZE == 3) {
          float4 v4 = *(const float4*)(pr + 20);   // phys(16tx+16) = 20tx+20
          w[16]=v4.x; w[17]=v4.y; w[18]=v4.z; w[19]=v4.w;
        }
      }
#pragma unroll
      for (int k = 0; k < KSIZE; k++) {
        const int j  = ii * KSIZE + k;
        const int g0 = SWZ ? (ty ^ (j >> 2)) : ty;
        const float* wp = &wls[j][g0 * 4];
        float4 a0 = *(const float4*)wp;
        float4 a1 = *(const float4*)(wp + 64);
        float a[8] = {a0.x, a0.y, a0.z, a0.w, a1.x, a1.y, a1.z, a1.w};
#pragma unroll
        for (int mo = 0; mo < 8; mo++)
#pragma unroll
          for (int nt = 0; nt < 16; nt++)
            acc[mo][nt] = fmaf(a[mo], w[nt + k], acc[mo][nt]);
      }
    }
  }

  const size_t outbase = (size_t)b * 256 * T;
#pragma unroll
  for (int mo = 0; mo < 8; mo++) {
    const int o = o0 + ty * 4 + (mo < 4 ? mo : 60 + mo);
    const float bd = gbias[o];
    const size_t rowb = outbase + (size_t)o * T + t0 + tx * 16;
#pragma unroll
    for (int h = 0; h < 4; h++) {
      const size_t off = rowb + (size_t)h * 4;
      float v[4];
#pragma unroll
      for (int c = 0; c < 4; c++) v[c] = acc[mo][h*4+c] + bd;
      if (RES && RELU) {                       // inner ReLU on h2
#pragma unroll
        for (int c = 0; c < 4; c++) v[c] = fmaxf(v[c], 0.f);
      }
      if (RES) {
        float4 rv = *(const float4*)(gres + off);
        v[0]+=rv.x; v[1]+=rv.y; v[2]+=rv.z; v[3]+=rv.w;
      }
      if (RELU) {
#pragma unroll
        for (int c = 0; c < 4; c++) v[c] = fmaxf(v[c], 0.f);
      }
      *(float4*)(gout + off) = make_float4(v[0], v[1], v[2], v[3]);
    }
  }
}

// ---------------- GEMM, f64 acc/out, BM=64 BN=128, 4x8 micro-tile ----
template<typename TA, typename TW, bool HASBIAS>
__global__ __launch_bounds__(256) void kgemm64d(
    const TA* __restrict__ A, const TW* __restrict__ W,
    const float* __restrict__ bias, double* __restrict__ C,
    int M, int N, int K)
{
  constexpr int BM = 64, BN = 128, BK = 16;
  __shared__ double As[BK][BM + 2];
  __shared__ double Ws[BK][BN + 2];
  const int tid = threadIdx.x;
  const int nx = tid & 15, my = tid >> 4;
  const int m0 = blockIdx.x * BM, n0 = blockIdx.y * BN;

  double acc[4][8];
#pragma unroll
  for (int i = 0; i < 4; i++)
#pragma unroll
    for (int j = 0; j < 8; j++) acc[i][j] = 0.0;

  for (int k0 = 0; k0 < K; k0 += BK) {
    __syncthreads();
    {
      int mm = tid >> 2, k4 = (tid & 3) * 4;
      const TA* ap = A + (size_t)(m0 + mm) * K + k0 + k4;
#pragma unroll
      for (int j = 0; j < 4; j++) As[k4 + j][mm] = (double)ap[j];
    }
#pragma unroll
    for (int r = 0; r < 8; r++) {
      int f = tid + r * 256;
      int kk = f >> 7, n = f & 127;
      Ws[kk][n] = (double)W[(size_t)(k0 + kk) * N + n0 + n];
    }
    __syncthreads();
#pragma unroll
    for (int k = 0; k < BK; k++) {
      double a[4], b[8];
#pragma unroll
      for (int i = 0; i < 4; i++) a[i] = As[k][my * 4 + i];
#pragma unroll
      for (int j = 0; j < 4; j++) { b[j] = Ws[k][nx * 4 + j]; b[4 + j] = Ws[k][nx * 4 + 64 + j]; }
#pragma unroll
      for (int i = 0; i < 4; i++)
#pragma unroll
        for (int j = 0; j < 8; j++)
          acc[i][j] = fma(a[i], b[j], acc[i][j]);
    }
  }

#pragma unroll
  for (int i = 0; i < 4; i++) {
    int m = m0 + my * 4 + i;
#pragma unroll
    for (int j = 0; j < 8; j++) {
      int n = n0 + nx * 4 + (j < 4 ? j : 60 + j);
      double v = acc[i][j];
      if (HASBIAS) v += (double)bias[n];
      C[(size_t)m * N + n] = v;
    }
  }
}

// ---------------- f32 transpose: out[Cc][R] = in[R][Cc], batched ----
__global__ __launch_bounds__(256) void ktrans(
    const float* __restrict__ in, float* __restrict__ out, int R, int Cc)
{
  __shared__ float tile[32][33];
  const int tx = threadIdx.x & 31, ty = threadIdx.x >> 5;
  const int c0 = blockIdx.x * 32, r0 = blockIdx.y * 32;
  const size_t zoff = (size_t)blockIdx.z * (size_t)R * Cc;
  const float* ib = in + zoff;
  float* ob = out + zoff;
#pragma unroll
  for (int s = 0; s < 32; s += 8)
    tile[ty + s][tx] = ib[(size_t)(r0 + ty + s) * Cc + c0 + tx];
  __syncthreads();
#pragma unroll
  for (int s = 0; s < 32; s += 8)
    ob[(size_t)(c0 + ty + s) * R + r0 + tx] = tile[tx][ty + s];
}

// ---------------- f64 transpose (codebook) ----
__global__ __launch_bounds__(256) void ktransd64(
    const double* __restrict__ in, double* __restrict__ out, int R, int Cc)
{
  __shared__ double tile[32][33];
  const int tx = threadIdx.x & 31, ty = threadIdx.x >> 5;
  const int c0 = blockIdx.x * 32, r0 = blockIdx.y * 32;
#pragma unroll
  for (int s = 0; s < 32; s += 8)
    tile[ty + s][tx] = in[(size_t)(r0 + ty + s) * Cc + c0 + tx];
  __syncthreads();
#pragma unroll
  for (int s = 0; s < 32; s += 8)
    out[(size_t)(c0 + ty + s) * R + r0 + tx] = tile[tx][ty + s];
}

// ---------------- codebook row norms f64 ----
__global__ __launch_bounds__(256) void kcnormd(const double* __restrict__ cb,
                                               double* __restrict__ cn)
{
  const int lane = threadIdx.x & 63, wid = threadIdx.x >> 6;
  const int row = blockIdx.x * 4 + wid;
  const double* x = cb + (size_t)row * 256;
  double s = 0.0;
#pragma unroll
  for (int c = 0; c < 4; c++) { double v = x[lane + 64 * c]; s = fma(v, v, s); }
#pragma unroll
  for (int d = 1; d < 64; d <<= 1) s += __shfl_xor(s, d, 64);
  if (lane == 0) cn[row] = s;
}

// ---------------- zero ints ----
__global__ __launch_bounds__(256) void kzero(int* __restrict__ p, int n)
{
  int i = blockIdx.x * 256 + threadIdx.x;
  if (i < n) p[i] = 0;
}

// ---------------- concat QKV weights/biases: qkvw[l][k][n], n<256:q,<512:k,else:v ----
__global__ __launch_bounds__(256) void kqkvcat(
    const float* __restrict__ wq, const float* __restrict__ wk,
    const float* __restrict__ wv, const float* __restrict__ bq,
    const float* __restrict__ bk, const float* __restrict__ bv,
    float* __restrict__ qkvw, float* __restrict__ qkvb)
{
  int idx = blockIdx.x * 256 + threadIdx.x;
  if (idx < 589824) {
    int l = idx / 196608;
    int rem = idx - l * 196608;
    int k = rem / 768, n = rem - k * 768;
    const float* src = (n < 256) ? wq : (n < 512) ? wk : wv;
    qkvw[idx] = src[(size_t)l * 65536 + k * 256 + (n & 255)];
  }
  if (idx < 2304) {
    int l = idx / 768, n = idx - l * 768;
    const float* sb = (n < 256) ? bq : (n < 512) ? bk : bv;
    qkvb[idx] = sb[l * 256 + (n & 255)];
  }
}

// ---------------- VQ per-row, all-f64 logits/argmax ----
__global__ __launch_bounds__(256) void kquantd(
    const double* __restrict__ q, const double* __restrict__ dot,
    const double* __restrict__ cn, const double* __restrict__ cb,
    float* __restrict__ rent, float* __restrict__ rsq,
    int* __restrict__ hist, float* __restrict__ h0, float* __restrict__ idxf)
{
  const int lane = threadIdx.x & 63, wid = threadIdx.x >> 6;
  const int n = blockIdx.x * 4 + wid;
  const double* qr = q + (size_t)n * 256;
  double qv[4];
#pragma unroll
  for (int c = 0; c < 4; c++) qv[c] = qr[lane + 64 * c];
  double qn = 0.0;
#pragma unroll
  for (int c = 0; c < 4; c++) qn = fma(qv[c], qv[c], qn);
#pragma unroll
  for (int d = 1; d < 64; d <<= 1) qn += __shfl_xor(qn, d, 64);

  const double* dr = dot + (size_t)n * 1024;
  double lg[16];
  double mx = -1.0e300; int bi = 0;
#pragma unroll
  for (int c = 0; c < 16; c++) {
    int j = lane + 64 * c;
    double l = -(qn + cn[j] - 2.0 * dr[j]);   // logits = -d (ETEMP=1)
    lg[c] = l;
    if (l > mx) { mx = l; bi = j; }
  }
#pragma unroll
  for (int d = 1; d < 64; d <<= 1) {
    double om = __shfl_xor(mx, d, 64);
    int    ob = __shfl_xor(bi, d, 64);
    if (om > mx || (om == mx && ob < bi)) { mx = om; bi = ob; }
  }
  float ssum = 0.f;
  float ef[16];
#pragma unroll
  for (int c = 0; c < 16; c++) { ef[c] = expf((float)(lg[c] - mx)); ssum += ef[c]; }
#pragma unroll
  for (int d = 1; d < 64; d <<= 1) ssum += __shfl_xor(ssum, d, 64);
  const float invs = 1.0f / ssum;
  float ent = 0.f;
#pragma unroll
  for (int c = 0; c < 16; c++) {
    float p = ef[c] * invs;
    ent -= p * logf(p + 1e-5f);
  }
#pragma unroll
  for (int d = 1; d < 64; d <<= 1) ent += __shfl_xor(ent, d, 64);

  const double* cbr = cb + (size_t)bi * 256;
  double sq = 0.0;
#pragma unroll
  for (int c = 0; c < 4; c++) {
    int col = lane + 64 * c;
    double z = cbr[col];
    double df = z - qv[c];
    sq = fma(df, df, sq);
    h0[(size_t)n * 256 + col] = (float)z;     // straight-through forward value
  }
#pragma unroll
  for (int d = 1; d < 64; d <<= 1) sq += __shfl_xor(sq, d, 64);

  if (lane == 0) {
    rent[n] = ent;
    rsq[n]  = (float)sq;
    atomicAdd(&hist[bi], 1);
    idxf[n] = (float)bi;
  }
}

// ---------------- final scalar loss ----
__global__ __launch_bounds__(256) void kloss(
    const float* __restrict__ rent, const float* __restrict__ rsq,
    const int* __restrict__ hist, float* __restrict__ outp)
{
  __shared__ float r0[256], r1[256], r2[256];
  const int tid = threadIdx.x;
  float se = 0.f, sq = 0.f, te = 0.f;
  for (int i = tid; i < 8192; i += 256) { se += rent[i]; sq += rsq[i]; }
  for (int j = tid; j < 1024; j += 256) {
    float a = (float)hist[j] * (1.0f / 8192.0f) + 1e-5f;
    te -= a * logf(a);
  }
  r0[tid] = se; r1[tid] = sq; r2[tid] = te;
  __syncthreads();
  for (int s = 128; s > 0; s >>= 1) {
    if (tid < s) { r0[tid] += r0[tid+s]; r1[tid] += r1[tid+s]; r2[tid] += r2[tid+s]; }
    __syncthreads();
  }
  if (tid == 0) {
    const float ln1024 = 6.9314718055994531f;
    float soft_ent  = r0[0] * (1.0f / 8192.0f);
    float soft_loss = 0.1f * (1.0f - soft_ent / ln1024);
    float vq        = 1.25f * (r1[0] / (8192.0f * 256.0f));
    float tok       = 0.1f * (1.0f - r2[0] / ln1024);
    outp[0] = vq + soft_loss + tok;
  }
}

// ---------------- generic fp32 GEMM (decoder/head) ----
template<bool HASBIAS, bool RES, int ACT>
__global__ __launch_bounds__(256) void kgemm(
    const float* __restrict__ A, const float* __restrict__ W,
    const float* __restrict__ bias, float* __restrict__ C,
    int M, int N, int K)
{
  constexpr int BM = 128, BN = 128, BK = 16;
  __shared__ float As[BK][BM + 4];
  __shared__ float Ws[BK][BN + 4];
  const int tid = threadIdx.x;
  const int nx = tid & 15, my = tid >> 4;
  const int m0 = blockIdx.x * BM, n0 = blockIdx.y * BN;

  float acc[8][8];
#pragma unroll
  for (int i = 0; i < 8; i++)
#pragma unroll
    for (int j = 0; j < 8; j++) acc[i][j] = 0.0f;

  for (int k0 = 0; k0 < K; k0 += BK) {
    __syncthreads();
#pragma unroll
    for (int rep = 0; rep < 2; rep++) {
      int id = tid + rep * 256;
      {
        int r = id >> 2, c4 = id & 3;
        float4 v = *(const float4*)(A + (size_t)(m0 + r) * K + k0 + c4 * 4);
        As[c4*4+0][r] = v.x; As[c4*4+1][r] = v.y;
        As[c4*4+2][r] = v.z; As[c4*4+3][r] = v.w;
      }
      {
        int kk = id >> 5, n4 = id & 31;
        int n = n0 + n4 * 4;
        float4 wv = make_float4(0.f, 0.f, 0.f, 0.f);
        if (n < N) wv = *(const float4*)(W + (size_t)(k0 + kk) * N + n);
        *(float4*)&Ws[kk][n4*4] = wv;
      }
    }
    __syncthreads();
#pragma unroll
    for (int k = 0; k < BK; k++) {
      float4 a0 = *(const float4*)&As[k][my*4];
      float4 a1 = *(const float4*)&As[k][my*4+64];
      float4 b0 = *(const float4*)&Ws[k][nx*4];
      float4 b1 = *(const float4*)&Ws[k][nx*4+64];
      float a[8]  = {a0.x,a0.y,a0.z,a0.w,a1.x,a1.y,a1.z,a1.w};
      float bb[8] = {b0.x,b0.y,b0.z,b0.w,b1.x,b1.y,b1.z,b1.w};
#pragma unroll
      for (int mo = 0; mo < 8; mo++)
#pragma unroll
        for (int nn = 0; nn < 8; nn++)
          acc[mo][nn] = fmaf(a[mo], bb[nn], acc[mo][nn]);
    }
  }

  float bv[8];
#pragma unroll
  for (int nn = 0; nn < 8; nn++) {
    int n = n0 + nx*4 + (nn < 4 ? nn : 60 + nn);
    bv[nn] = (HASBIAS && n < N) ? bias[n] : 0.0f;
  }
#pragma unroll
  for (int mo = 0; mo < 8; mo++) {
    int m = m0 + my*4 + (mo < 4 ? mo : 60 + mo);
#pragma unroll
    for (int h = 0; h < 2; h++) {
      int n = n0 + nx*4 + h*64;
      if (n < N) {
        size_t off = (size_t)m * N + n;
        float v[4];
#pragma unroll
        for (int c = 0; c < 4; c++) v[c] = acc[mo][h*4+c] + bv[h*4+c];
        if (RES) {
          float4 rv = *(const float4*)(C + off);
          v[0]+=rv.x; v[1]+=rv.y; v[2]+=rv.z; v[3]+=rv.w;
        }
        if (ACT == 1) {
#pragma unroll
          for (int c = 0; c < 4; c++) v[c] = geluf(v[c]);
        }
        *(float4*)(C + off) = make_float4(v[0],v[1],v[2],v[3]);
      }
    }
  }
}

// ---------------- layernorm ----
__global__ __launch_bounds__(256) void kln(
    const float* __restrict__ X, const float* __restrict__ gs,
    const float* __restrict__ gb, float* __restrict__ Y)
{
  const int lane = threadIdx.x & 63, wid = threadIdx.x >> 6;
  const int row = blockIdx.x * 4 + wid;
  const float* x = X + (size_t)row * 256;
  float v[4];
#pragma unroll
  for (int c = 0; c < 4; c++) v[c] = x[lane + 64*c];
  float s = v[0]+v[1]+v[2]+v[3];
#pragma unroll
  for (int d = 1; d < 64; d <<= 1) s += __shfl_xor(s, d, 64);
  const float m = s * (1.0f/256.0f);
  float vr = 0.f;
#pragma unroll
  for (int c = 0; c < 4; c++) { float dd = v[c]-m; vr = fmaf(dd, dd, vr); }
#pragma unroll
  for (int d = 1; d < 64; d <<= 1) vr += __shfl_xor(vr, d, 64);
  const float inv = 1.0f / sqrtf(vr * (1.0f/256.0f) + 1e-5f);
  float* y = Y + (size_t)row * 256;
#pragma unroll
  for (int c = 0; c < 4; c++) {
    int col = lane + 64*c;
    y[col] = (v[c]-m) * inv * gs[col] + gb[col];
  }
}

// ---------------- causal attention; QKV packed [8192][768] (q|k|v) ----
__global__ __launch_bounds__(128) void kattn(
    const float* __restrict__ QKV, float* __restrict__ O)
{
  __shared__ float ks[128][64];
  __shared__ float vs[128][64];
  const int h = blockIdx.x, b = blockIdx.y;
  const int tid = threadIdx.x;
  const size_t rbase = (size_t)b * 128;
  {
    const float* kp0 = QKV + (rbase + tid) * 768 + 256 + h * 64;
    const float* vp0 = kp0 + 256;
    const float4* kp = (const float4*)kp0;
    const float4* vp = (const float4*)vp0;
    float4* kd = (float4*)&ks[tid][0];
    float4* vd = (float4*)&vs[tid][0];
#pragma unroll
    for (int c = 0; c < 16; c++) { kd[c] = kp[c]; vd[c] = vp[c]; }
  }
  __syncthreads();
  const int i = tid;
  float qr[64];
  {
    const float4* qp = (const float4*)(QKV + (rbase + i) * 768 + h * 64);
#pragma unroll
    for (int c = 0; c < 16; c++) {
      float4 v = qp[c];
      qr[c*4+0]=v.x; qr[c*4+1]=v.y; qr[c*4+2]=v.z; qr[c*4+3]=v.w;
    }
  }
  float mx = -3.4e38f;
  for (int j = 0; j <= i; j++) {
    float s = 0.f;
#pragma unroll
    for (int d = 0; d < 64; d++) s = fmaf(qr[d], ks[j][d], s);
    mx = fmaxf(mx, s * 0.125f);
  }
  float den = 0.f;
  float o[64];
#pragma unroll
  for (int d = 0; d < 64; d++) o[d] = 0.f;
  for (int j = 0; j <= i; j++) {
    float s = 0.f;
#pragma unroll
    for (int d = 0; d < 64; d++) s = fmaf(qr[d], ks[j][d], s);
    float p = expf(s * 0.125f - mx);
    den += p;
#pragma unroll
    for (int d = 0; d < 64; d++) o[d] = fmaf(p, vs[j][d], o[d]);
  }
  const float inv = 1.0f / den;
  float* op = O + (rbase + i) * 256 + h * 64;
#pragma unroll
  for (int c = 0; c < 16; c++)
    *(float4*)(op + c*4) = make_float4(o[c*4]*inv, o[c*4+1]*inv,
                                       o[c*4+2]*inv, o[c*4+3]*inv);
}

// ---------------------------------------------------------------------------
extern "C" void kernel_launch(void* const* d_in, const int* in_sizes, int n_in,
                              void* d_out, int out_size, void* d_ws, size_t ws_size,
                              hipStream_t stream)
{
  (void)n_in; (void)out_size;
  if (ws_size < (size_t)268435456) return;

  const int o = (in_sizes[1] == 114688) ? 0 : -1;
  const float* x     = (const float*)d_in[0];
  const float* t0w1  = (const float*)d_in[2+o];
  const float* t0b1  = (const float*)d_in[3+o];
  const float* t0w2  = (const float*)d_in[4+o];
  const float* t0b2  = (const float*)d_in[5+o];
  const float* t0dw  = (const float*)d_in[6+o];
  const float* t0db  = (const float*)d_in[7+o];
  const float* t1w1  = (const float*)d_in[8+o];
  const float* t1b1  = (const float*)d_in[9+o];
  const float* t1w2  = (const float*)d_in[10+o];
  const float* t1b2  = (const float*)d_in[11+o];
  const float* t2w1  = (const float*)d_in[12+o];
  const float* t2b1  = (const float*)d_in[13+o];
  const float* t2w2  = (const float*)d_in[14+o];
  const float* t2b2  = (const float*)d_in[15+o];
  const float* qinw  = (const float*)d_in[16+o];
  const float* qinb  = (const float*)d_in[17+o];
  const float* emb   = (const float*)d_in[18+o];
  const float* projw = (const float*)d_in[19+o];
  const float* projb = (const float*)d_in[20+o];
  const float* ln1s  = (const float*)d_in[21+o];
  const float* ln1b  = (const float*)d_in[22+o];
  const float* wq    = (const float*)d_in[23+o];
  const float* bq    = (const float*)d_in[24+o];
  const float* wk    = (const float*)d_in[25+o];
  const float* bk    = (const float*)d_in[26+o];
  const float* wv    = (const float*)d_in[27+o];
  const float* bv    = (const float*)d_in[28+o];
  const float* wo    = (const float*)d_in[29+o];
  const float* bo    = (const float*)d_in[30+o];
  const float* ln2s  = (const float*)d_in[31+o];
  const float* ln2b  = (const float*)d_in[32+o];
  const float* fw1   = (const float*)d_in[33+o];
  const float* fb1   = (const float*)d_in[34+o];
  const float* fw2   = (const float*)d_in[35+o];
  const float* fb2   = (const float*)d_in[36+o];
  const float* hw1   = (const float*)d_in[37+o];
  const float* hb1   = (const float*)d_in[38+o];
  const float* hw2   = (const float*)d_in[39+o];
  const float* hb2   = (const float*)d_in[40+o];
  float* outp = (float*)d_out;
  float* fws  = (float*)d_ws;

  // ---- workspace (67,108,864 floats = 256 MB) ----
  float* fA = fws;                          // [64][256][2048] f32 ping (128 MB)
  float* fB = fws + (size_t)33554432;       // [64][256][2048] f32 pong (128 MB)
  // fB region after enc is consumed (post-transpose):
  float*  qwT32 = fB;                                   // [4096][256] f32 (4 MB)
  double* q64   = (double*)(fB + (size_t)1048576);      // [8192][256] f64 (16 MB)
  double* cb64  = q64  + (size_t)2097152;               // [1024][256] f64 (2 MB)
  double* cbT64 = cb64 + (size_t)262144;                // [256][1024] f64 (2 MB)
  double* cn64  = cbT64 + (size_t)262144;               // [1024] f64
  double* dot64 = cn64 + 1024;                          // [8192][1024] f64 (64 MB)
  float*  rent  = (float*)(dot64 + (size_t)8388608);    // [8192] f32
  float*  rsq   = rent + 8192;                          // [8192]
  int*    hist  = (int*)(rsq + 8192);                   // [1024]
  // fA region after patches are consumed (post q-GEMM): decoder buffers
  float* hbuf = fA;                          // [8192][256]
  float* Nb   = hbuf + (size_t)2097152;      // [8192][256]
  float* QKVb = Nb   + (size_t)2097152;      // [8192][768]  (6.29M)
  float* Ob   = QKVb + (size_t)6291456;      // [8192][256]  ends 12.58M
  float* F1   = fA + (size_t)12582912;       // [8192][1024] ends 20.97M
  float* Gb   = fA + (size_t)20971520;       // [8192][512]  ends 25.17M
  float* qkvw = fA + (size_t)25165824;       // [3][256][768] (589,824)
  float* qkvb = qkvw + (size_t)589824;       // [3][768]     ends ~25.76M (<33.55M)

  // ---- TCN fp32, full batch (BT=256, BO=128, 3 blocks/CU) ----
  dim3 cgrid(8, 2, 64);
  kconv32<7,3,true ,false,true ><<<cgrid, 256, 0, stream>>>(x, t0w1, t0b1, fA, nullptr);
  kconv32<7,1,true ,false,false><<<cgrid, 256, 0, stream>>>(x, t0dw, t0db, fB, nullptr);
  kconv32<256,3,false,true ,true ><<<cgrid, 256, 0, stream>>>(fA, t0w2, t0b2, fB, fB);
  kconv32<256,3,false,false,true ><<<cgrid, 256, 0, stream>>>(fB, t1w1, t1b1, fA, nullptr);
  kconv32<256,3,false,true ,true ><<<cgrid, 256, 0, stream>>>(fA, t1w2, t1b2, fB, fB);
  kconv32<256,3,false,false,true ><<<cgrid, 256, 0, stream>>>(fB, t2w1, t2b1, fA, nullptr);
  kconv32<256,3,false,true ,true ><<<cgrid, 256, 0, stream>>>(fA, t2w2, t2b2, fB, fB);

  // enc [b][256][2048] (fB) -> patches [b][2048][256] (fA); fB now dead
  ktrans<<<dim3(64, 8, 64), 256, 0, stream>>>(fB, fA, 256, 2048);
  // qin_w [256][4096] -> qwT32 [4096][256]
  ktrans<<<dim3(128, 8, 1), 256, 0, stream>>>(qinw, qwT32, 256, 4096);

  // ---- sensitive tail in f64 ----
  kgemm64d<float,float,true><<<dim3(128, 2), 256, 0, stream>>>(
      fA, qwT32, qinb, q64, 8192, 256, 4096);
  kgemm64d<float,float,true><<<dim3(16, 2), 256, 0, stream>>>(
      emb, projw, projb, cb64, 1024, 256, 256);
  ktransd64<<<dim3(8, 32, 1), 256, 0, stream>>>(cb64, cbT64, 1024, 256);
  kcnormd<<<256, 256, 0, stream>>>(cb64, cn64);
  kgemm64d<double,double,false><<<dim3(128, 8), 256, 0, stream>>>(
      q64, cbT64, nullptr, dot64, 8192, 1024, 256);
  kzero<<<4, 256, 0, stream>>>(hist, 1024);
  kquantd<<<2048, 256, 0, stream>>>(q64, dot64, cn64, cb64, rent, rsq, hist,
                                    hbuf, outp + 917505);
  kloss<<<1, 256, 0, stream>>>(rent, rsq, hist, outp + 917504);

  // ---- transformer decoder (fp32), fused QKV ----
  kqkvcat<<<2304, 256, 0, stream>>>(wq, wk, wv, bq, bk, bv, qkvw, qkvb);
  for (int l = 0; l < 3; l++) {
    kln<<<2048, 256, 0, stream>>>(hbuf, ln1s + l*256, ln1b + l*256, Nb);
    kgemm<true,false,0><<<dim3(64, 6), 256, 0, stream>>>(Nb, qkvw + (size_t)l*196608, qkvb + l*768, QKVb, 8192, 768, 256);
    kattn<<<dim3(4, 64), 128, 0, stream>>>(QKVb, Ob);
    kgemm<true,true ,0><<<dim3(64, 2), 256, 0, stream>>>(Ob, wo + (size_t)l*65536, bo + l*256, hbuf, 8192, 256, 256);
    kln<<<2048, 256, 0, stream>>>(hbuf, ln2s + l*256, ln2b + l*256, Nb);
    kgemm<true,false,1><<<dim3(64, 8), 256, 0, stream>>>(Nb, fw1 + (size_t)l*262144, fb1 + l*1024, F1, 8192, 1024, 256);
    kgemm<true,true ,0><<<dim3(64, 2), 256, 0, stream>>>(F1, fw2 + (size_t)l*262144, fb2 + l*256, hbuf, 8192, 256, 1024);
  }
  // ---- head ----
  kgemm<true,false,1><<<dim3(64, 4), 256, 0, stream>>>(hbuf, hw1, hb1, Gb, 8192, 512, 256);
  kgemm<true,false,0><<<dim3(64, 1), 256, 0, stream>>>(Gb, hw2, hb2, outp, 8192, 112, 512);
}

// Round 20
// 5359.477 us; speedup vs baseline: 2.5106x; 2.5106x over previous
//
#include <hip/hip_runtime.h>
#include <cstddef>

// ---------------------------------------------------------------------------
// VQVAE forward. r18 config (best measured 5.62 ms): conv BO=256/512thr
// launch_bounds(512,2) (VGPR 120, no spill). NEW: kgemmN (BM=64,BN=128 fp32,
// float clone of proven kgemm64d) for the two half-grid N=256 decoder GEMMs
// (wo-proj, FFN2) -> 256 blocks instead of 128. Per-element k-order identical
// -> bit-identical outputs. Conv track closed: launch-bounds occupancy floors
// 3x caused VGPR clamp+spill (r12/r17/r19); staged-bytes falsified (r18).
// TCN block: out = relu( relu(conv2(relu(conv1+b1))+b2) + res ).
// Workspace 256 MB.
// ---------------------------------------------------------------------------

static __device__ __forceinline__ float geluf(float x) {
  return 0.5f * x * (1.0f + erff(x * 0.70710678118654752440f));
}

// ---------------- fp32 conv: out[b][o][t] over [B][C][T], full batch ----
template<int CIN, int KSIZE, bool FROMX, bool RES, bool RELU, int BO, int NT>
__global__ __launch_bounds__(NT, 2) void kconv32(
    const float* __restrict__ gin, const float* __restrict__ gw,
    const float* __restrict__ gbias, float* __restrict__ gout,
    const float* __restrict__ gres)
{
  constexpr int BT = 256;
  constexpr int PAD = KSIZE - 1;          // causal left pad
  constexpr int KI = (CIN < 16) ? CIN : 16;
  constexpr int JW = KI * KSIZE;
  constexpr int UW = BT + PAD;
  constexpr int UW_S = (KSIZE == 3) ? (UW + 2) : UW;   // stage through halo b128
  constexpr int RS = (UW_S - 1) + (((UW_S - 1) >> 4) << 2) + 1;  // skewed row size
  constexpr int T = 2048;
  constexpr bool SWZ = (CIN >= 16);       // swizzled weight staging (JW%4==0)
  constexpr int WSZ = (KSIZE == 3) ? 20 : 16;
  constexpr int HALF = BO / 2;

  __shared__ float ins[KI][RS];
  __shared__ float wls[JW][BO];

  const int tid = threadIdx.x;
  const int tx = tid & 15, ty = tid >> 4;
  const int t0 = blockIdx.x * BT;
  const int o0 = blockIdx.y * BO;
  const int b  = blockIdx.z;

  const float* inb = gin + (FROMX ? (size_t)b * T * 7 : (size_t)b * 256 * T);

  float acc[8][16];
#pragma unroll
  for (int i = 0; i < 8; i++)
#pragma unroll
    for (int j = 0; j < 16; j++) acc[i][j] = 0.0f;

  for (int i0 = 0; i0 < CIN; i0 += KI) {
    __syncthreads();
    for (int f = tid; f < KI * UW_S; f += NT) {
      int ii = f / UW_S, u = f - ii * UW_S;
      int t = t0 - PAD + u;
      float v = 0.0f;
      if (t >= 0 && t < T) v = FROMX ? inb[t * 7 + (i0 + ii)]
                                     : inb[(size_t)(i0 + ii) * T + t];
      ins[ii][u + ((u >> 4) << 2)] = v;
    }
    if constexpr (SWZ) {
#pragma unroll
      for (int r = 0; r < (JW * BO / 4 + NT - 1) / NT; r++) {
        int f = tid + r * NT;
        int oo = f / (JW / 4);
        int jq = f - oo * (JW / 4);
        int j  = jq * 4;
        const float4 w4 = *(const float4*)&gw[(size_t)(o0 + oo) * (CIN * KSIZE)
                                              + (size_t)i0 * KSIZE + j];
        const int col = (((oo >> 2) ^ jq) << 2) | (oo & 3);
        wls[j + 0][col] = w4.x;
        wls[j + 1][col] = w4.y;
        wls[j + 2][col] = w4.z;
        wls[j + 3][col] = w4.w;
      }
    } else {
      for (int f = tid; f < JW * BO; f += NT) {
        int j = f / BO, oo = f - j * BO;
        wls[j][oo] = gw[(size_t)(o0 + oo) * (CIN * KSIZE) + (size_t)i0 * KSIZE + j];
      }
    }
    __syncthreads();
#pragma unroll
    for (int ii = 0; ii < KI; ii++) {
      float w[WSZ];
      {
        const float* pr = &ins[ii][20 * tx];
        float4 v0 = *(const float4*)(pr + 0);
        float4 v1 = *(const float4*)(pr + 4);
        float4 v2 = *(const float4*)(pr + 8);
        float4 v3 = *(const float4*)(pr + 12);
        w[0]=v0.x; w[1]=v0.y; w[2]=v0.z; w[3]=v0.w;
        w[4]=v1.x; w[5]=v1.y; w[6]=v1.z; w[7]=v1.w;
        w[8]=v2.x; w[9]=v2.y; w[10]=v2.z; w[11]=v2.w;
        w[12]=v3.x; w[13]=v3.y; w[14]=v3.z; w[15]=v3.w;
        if constexpr (KSIZE == 3) {
          float4 v4 = *(const float4*)(pr + 20);
          w[16]=v4.x; w[17]=v4.y; w[18]=v4.z; w[19]=v4.w;
        }
      }
#pragma unroll
      for (int k = 0; k < KSIZE; k++) {
        const int j  = ii * KSIZE + k;
        const int g0 = SWZ ? (ty ^ (j >> 2)) : ty;
        const float* wp = &wls[j][g0 * 4];
        float4 a0 = *(const float4*)wp;
        float4 a1 = *(const float4*)(wp + HALF);
        float a[8] = {a0.x, a0.y, a0.z, a0.w, a1.x, a1.y, a1.z, a1.w};
#pragma unroll
        for (int mo = 0; mo < 8; mo++)
#pragma unroll
          for (int nt = 0; nt < 16; nt++)
            acc[mo][nt] = fmaf(a[mo], w[nt + k], acc[mo][nt]);
      }
    }
  }

  const size_t outbase = (size_t)b * 256 * T;
#pragma unroll
  for (int mo = 0; mo < 8; mo++) {
    const int o = o0 + ty * 4 + (mo < 4 ? mo : (HALF - 4) + mo);
    const float bd = gbias[o];
    const size_t rowb = outbase + (size_t)o * T + t0 + tx * 16;
#pragma unroll
    for (int h = 0; h < 4; h++) {
      const size_t off = rowb + (size_t)h * 4;
      float v[4];
#pragma unroll
      for (int c = 0; c < 4; c++) v[c] = acc[mo][h*4+c] + bd;
      if (RES && RELU) {                       // inner ReLU on h2
#pragma unroll
        for (int c = 0; c < 4; c++) v[c] = fmaxf(v[c], 0.f);
      }
      if (RES) {
        float4 rv = *(const float4*)(gres + off);
        v[0]+=rv.x; v[1]+=rv.y; v[2]+=rv.z; v[3]+=rv.w;
      }
      if (RELU) {
#pragma unroll
        for (int c = 0; c < 4; c++) v[c] = fmaxf(v[c], 0.f);
      }
      *(float4*)(gout + off) = make_float4(v[0], v[1], v[2], v[3]);
    }
  }
}

// ---------------- GEMM, f64 acc/out, BM=64 BN=128, 4x8 micro-tile ----
template<typename TA, typename TW, bool HASBIAS>
__global__ __launch_bounds__(256) void kgemm64d(
    const TA* __restrict__ A, const TW* __restrict__ W,
    const float* __restrict__ bias, double* __restrict__ C,
    int M, int N, int K)
{
  constexpr int BM = 64, BN = 128, BK = 16;
  __shared__ double As[BK][BM + 2];
  __shared__ double Ws[BK][BN + 2];
  const int tid = threadIdx.x;
  const int nx = tid & 15, my = tid >> 4;
  const int m0 = blockIdx.x * BM, n0 = blockIdx.y * BN;

  double acc[4][8];
#pragma unroll
  for (int i = 0; i < 4; i++)
#pragma unroll
    for (int j = 0; j < 8; j++) acc[i][j] = 0.0;

  for (int k0 = 0; k0 < K; k0 += BK) {
    __syncthreads();
    {
      int mm = tid >> 2, k4 = (tid & 3) * 4;
      const TA* ap = A + (size_t)(m0 + mm) * K + k0 + k4;
#pragma unroll
      for (int j = 0; j < 4; j++) As[k4 + j][mm] = (double)ap[j];
    }
#pragma unroll
    for (int r = 0; r < 8; r++) {
      int f = tid + r * 256;
      int kk = f >> 7, n = f & 127;
      Ws[kk][n] = (double)W[(size_t)(k0 + kk) * N + n0 + n];
    }
    __syncthreads();
#pragma unroll
    for (int k = 0; k < BK; k++) {
      double a[4], b[8];
#pragma unroll
      for (int i = 0; i < 4; i++) a[i] = As[k][my * 4 + i];
#pragma unroll
      for (int j = 0; j < 4; j++) { b[j] = Ws[k][nx * 4 + j]; b[4 + j] = Ws[k][nx * 4 + 64 + j]; }
#pragma unroll
      for (int i = 0; i < 4; i++)
#pragma unroll
        for (int j = 0; j < 8; j++)
          acc[i][j] = fma(a[i], b[j], acc[i][j]);
    }
  }

#pragma unroll
  for (int i = 0; i < 4; i++) {
    int m = m0 + my * 4 + i;
#pragma unroll
    for (int j = 0; j < 8; j++) {
      int n = n0 + nx * 4 + (j < 4 ? j : 60 + j);
      double v = acc[i][j];
      if (HASBIAS) v += (double)bias[n];
      C[(size_t)m * N + n] = v;
    }
  }
}

// ---------------- fp32 GEMM, BM=64 BN=128 (full-grid N=256 decoder GEMMs) ----
template<bool HASBIAS, bool RES, int ACT>
__global__ __launch_bounds__(256) void kgemmN(
    const float* __restrict__ A, const float* __restrict__ W,
    const float* __restrict__ bias, float* __restrict__ C,
    int M, int N, int K)
{
  constexpr int BM = 64, BN = 128, BK = 16;
  __shared__ float As[BK][BM + 4];
  __shared__ float Ws[BK][BN + 4];
  const int tid = threadIdx.x;
  const int nx = tid & 15, my = tid >> 4;
  const int m0 = blockIdx.x * BM, n0 = blockIdx.y * BN;

  float acc[4][8];
#pragma unroll
  for (int i = 0; i < 4; i++)
#pragma unroll
    for (int j = 0; j < 8; j++) acc[i][j] = 0.0f;

  for (int k0 = 0; k0 < K; k0 += BK) {
    __syncthreads();
    {
      int mm = tid >> 2, k4 = (tid & 3) * 4;
      float4 v = *(const float4*)(A + (size_t)(m0 + mm) * K + k0 + k4);
      As[k4+0][mm] = v.x; As[k4+1][mm] = v.y;
      As[k4+2][mm] = v.z; As[k4+3][mm] = v.w;
    }
#pragma unroll
    for (int rep = 0; rep < 2; rep++) {
      int id = tid + rep * 256;
      int kk = id >> 5, n4 = id & 31;
      float4 wv = *(const float4*)(W + (size_t)(k0 + kk) * N + n0 + n4 * 4);
      *(float4*)&Ws[kk][n4*4] = wv;
    }
    __syncthreads();
#pragma unroll
    for (int k = 0; k < BK; k++) {
      float4 af = *(const float4*)&As[k][my*4];
      float4 b0 = *(const float4*)&Ws[k][nx*4];
      float4 b1 = *(const float4*)&Ws[k][nx*4+64];
      float a[4]  = {af.x, af.y, af.z, af.w};
      float bb[8] = {b0.x,b0.y,b0.z,b0.w,b1.x,b1.y,b1.z,b1.w};
#pragma unroll
      for (int i = 0; i < 4; i++)
#pragma unroll
        for (int j = 0; j < 8; j++)
          acc[i][j] = fmaf(a[i], bb[j], acc[i][j]);
    }
  }

  float bv[8];
#pragma unroll
  for (int j = 0; j < 8; j++) {
    int n = n0 + nx*4 + (j < 4 ? j : 60 + j);
    bv[j] = HASBIAS ? bias[n] : 0.0f;
  }
#pragma unroll
  for (int i = 0; i < 4; i++) {
    int m = m0 + my * 4 + i;
#pragma unroll
    for (int h = 0; h < 2; h++) {
      int n = n0 + nx*4 + h*64;
      size_t off = (size_t)m * N + n;
      float v[4];
#pragma unroll
      for (int c = 0; c < 4; c++) v[c] = acc[i][h*4+c] + bv[h*4+c];
      if (RES) {
        float4 rv = *(const float4*)(C + off);
        v[0]+=rv.x; v[1]+=rv.y; v[2]+=rv.z; v[3]+=rv.w;
      }
      if (ACT == 1) {
#pragma unroll
        for (int c = 0; c < 4; c++) v[c] = geluf(v[c]);
      }
      *(float4*)(C + off) = make_float4(v[0],v[1],v[2],v[3]);
    }
  }
}

// ---------------- f32 transpose: out[Cc][R] = in[R][Cc], batched ----
__global__ __launch_bounds__(256) void ktrans(
    const float* __restrict__ in, float* __restrict__ out, int R, int Cc)
{
  __shared__ float tile[32][33];
  const int tx = threadIdx.x & 31, ty = threadIdx.x >> 5;
  const int c0 = blockIdx.x * 32, r0 = blockIdx.y * 32;
  const size_t zoff = (size_t)blockIdx.z * (size_t)R * Cc;
  const float* ib = in + zoff;
  float* ob = out + zoff;
#pragma unroll
  for (int s = 0; s < 32; s += 8)
    tile[ty + s][tx] = ib[(size_t)(r0 + ty + s) * Cc + c0 + tx];
  __syncthreads();
#pragma unroll
  for (int s = 0; s < 32; s += 8)
    ob[(size_t)(c0 + ty + s) * R + r0 + tx] = tile[tx][ty + s];
}

// ---------------- f64 transpose (codebook) ----
__global__ __launch_bounds__(256) void ktransd64(
    const double* __restrict__ in, double* __restrict__ out, int R, int Cc)
{
  __shared__ double tile[32][33];
  const int tx = threadIdx.x & 31, ty = threadIdx.x >> 5;
  const int c0 = blockIdx.x * 32, r0 = blockIdx.y * 32;
#pragma unroll
  for (int s = 0; s < 32; s += 8)
    tile[ty + s][tx] = in[(size_t)(r0 + ty + s) * Cc + c0 + tx];
  __syncthreads();
#pragma unroll
  for (int s = 0; s < 32; s += 8)
    out[(size_t)(c0 + ty + s) * R + r0 + tx] = tile[tx][ty + s];
}

// ---------------- codebook row norms f64 ----
__global__ __launch_bounds__(256) void kcnormd(const double* __restrict__ cb,
                                               double* __restrict__ cn)
{
  const int lane = threadIdx.x & 63, wid = threadIdx.x >> 6;
  const int row = blockIdx.x * 4 + wid;
  const double* x = cb + (size_t)row * 256;
  double s = 0.0;
#pragma unroll
  for (int c = 0; c < 4; c++) { double v = x[lane + 64 * c]; s = fma(v, v, s); }
#pragma unroll
  for (int d = 1; d < 64; d <<= 1) s += __shfl_xor(s, d, 64);
  if (lane == 0) cn[row] = s;
}

// ---------------- zero ints ----
__global__ __launch_bounds__(256) void kzero(int* __restrict__ p, int n)
{
  int i = blockIdx.x * 256 + threadIdx.x;
  if (i < n) p[i] = 0;
}

// ---------------- concat QKV weights/biases ----
__global__ __launch_bounds__(256) void kqkvcat(
    const float* __restrict__ wq, const float* __restrict__ wk,
    const float* __restrict__ wv, const float* __restrict__ bq,
    const float* __restrict__ bk, const float* __restrict__ bv,
    float* __restrict__ qkvw, float* __restrict__ qkvb)
{
  int idx = blockIdx.x * 256 + threadIdx.x;
  if (idx < 589824) {
    int l = idx / 196608;
    int rem = idx - l * 196608;
    int k = rem / 768, n = rem - k * 768;
    const float* src = (n < 256) ? wq : (n < 512) ? wk : wv;
    qkvw[idx] = src[(size_t)l * 65536 + k * 256 + (n & 255)];
  }
  if (idx < 2304) {
    int l = idx / 768, n = idx - l * 768;
    const float* sb = (n < 256) ? bq : (n < 512) ? bk : bv;
    qkvb[idx] = sb[l * 256 + (n & 255)];
  }
}

// ---------------- VQ per-row, all-f64 logits/argmax ----
__global__ __launch_bounds__(256) void kquantd(
    const double* __restrict__ q, const double* __restrict__ dot,
    const double* __restrict__ cn, const double* __restrict__ cb,
    float* __restrict__ rent, float* __restrict__ rsq,
    int* __restrict__ hist, float* __restrict__ h0, float* __restrict__ idxf)
{
  const int lane = threadIdx.x & 63, wid = threadIdx.x >> 6;
  const int n = blockIdx.x * 4 + wid;
  const double* qr = q + (size_t)n * 256;
  double qv[4];
#pragma unroll
  for (int c = 0; c < 4; c++) qv[c] = qr[lane + 64 * c];
  double qn = 0.0;
#pragma unroll
  for (int c = 0; c < 4; c++) qn = fma(qv[c], qv[c], qn);
#pragma unroll
  for (int d = 1; d < 64; d <<= 1) qn += __shfl_xor(qn, d, 64);

  const double* dr = dot + (size_t)n * 1024;
  double lg[16];
  double mx = -1.0e300; int bi = 0;
#pragma unroll
  for (int c = 0; c < 16; c++) {
    int j = lane + 64 * c;
    double l = -(qn + cn[j] - 2.0 * dr[j]);   // logits = -d (ETEMP=1)
    lg[c] = l;
    if (l > mx) { mx = l; bi = j; }
  }
#pragma unroll
  for (int d = 1; d < 64; d <<= 1) {
    double om = __shfl_xor(mx, d, 64);
    int    ob = __shfl_xor(bi, d, 64);
    if (om > mx || (om == mx && ob < bi)) { mx = om; bi = ob; }
  }
  float ssum = 0.f;
  float ef[16];
#pragma unroll
  for (int c = 0; c < 16; c++) { ef[c] = expf((float)(lg[c] - mx)); ssum += ef[c]; }
#pragma unroll
  for (int d = 1; d < 64; d <<= 1) ssum += __shfl_xor(ssum, d, 64);
  const float invs = 1.0f / ssum;
  float ent = 0.f;
#pragma unroll
  for (int c = 0; c < 16; c++) {
    float p = ef[c] * invs;
    ent -= p * logf(p + 1e-5f);
  }
#pragma unroll
  for (int d = 1; d < 64; d <<= 1) ent += __shfl_xor(ent, d, 64);

  const double* cbr = cb + (size_t)bi * 256;
  double sq = 0.0;
#pragma unroll
  for (int c = 0; c < 4; c++) {
    int col = lane + 64 * c;
    double z = cbr[col];
    double df = z - qv[c];
    sq = fma(df, df, sq);
    h0[(size_t)n * 256 + col] = (float)z;     // straight-through forward value
  }
#pragma unroll
  for (int d = 1; d < 64; d <<= 1) sq += __shfl_xor(sq, d, 64);

  if (lane == 0) {
    rent[n] = ent;
    rsq[n]  = (float)sq;
    atomicAdd(&hist[bi], 1);
    idxf[n] = (float)bi;
  }
}

// ---------------- final scalar loss ----
__global__ __launch_bounds__(256) void kloss(
    const float* __restrict__ rent, const float* __restrict__ rsq,
    const int* __restrict__ hist, float* __restrict__ outp)
{
  __shared__ float r0[256], r1[256], r2[256];
  const int tid = threadIdx.x;
  float se = 0.f, sq = 0.f, te = 0.f;
  for (int i = tid; i < 8192; i += 256) { se += rent[i]; sq += rsq[i]; }
  for (int j = tid; j < 1024; j += 256) {
    float a = (float)hist[j] * (1.0f / 8192.0f) + 1e-5f;
    te -= a * logf(a);
  }
  r0[tid] = se; r1[tid] = sq; r2[tid] = te;
  __syncthreads();
  for (int s = 128; s > 0; s >>= 1) {
    if (tid < s) { r0[tid] += r0[tid+s]; r1[tid] += r1[tid+s]; r2[tid] += r2[tid+s]; }
    __syncthreads();
  }
  if (tid == 0) {
    const float ln1024 = 6.9314718055994531f;
    float soft_ent  = r0[0] * (1.0f / 8192.0f);
    float soft_loss = 0.1f * (1.0f - soft_ent / ln1024);
    float vq        = 1.25f * (r1[0] / (8192.0f * 256.0f));
    float tok       = 0.1f * (1.0f - r2[0] / ln1024);
    outp[0] = vq + soft_loss + tok;
  }
}

// ---------------- generic fp32 GEMM (BM=128; QKV/FFN1/head) ----
template<bool HASBIAS, bool RES, int ACT>
__global__ __launch_bounds__(256) void kgemm(
    const float* __restrict__ A, const float* __restrict__ W,
    const float* __restrict__ bias, float* __restrict__ C,
    int M, int N, int K)
{
  constexpr int BM = 128, BN = 128, BK = 16;
  __shared__ float As[BK][BM + 4];
  __shared__ float Ws[BK][BN + 4];
  const int tid = threadIdx.x;
  const int nx = tid & 15, my = tid >> 4;
  const int m0 = blockIdx.x * BM, n0 = blockIdx.y * BN;

  float acc[8][8];
#pragma unroll
  for (int i = 0; i < 8; i++)
#pragma unroll
    for (int j = 0; j < 8; j++) acc[i][j] = 0.0f;

  for (int k0 = 0; k0 < K; k0 += BK) {
    __syncthreads();
#pragma unroll
    for (int rep = 0; rep < 2; rep++) {
      int id = tid + rep * 256;
      {
        int r = id >> 2, c4 = id & 3;
        float4 v = *(const float4*)(A + (size_t)(m0 + r) * K + k0 + c4 * 4);
        As[c4*4+0][r] = v.x; As[c4*4+1][r] = v.y;
        As[c4*4+2][r] = v.z; As[c4*4+3][r] = v.w;
      }
      {
        int kk = id >> 5, n4 = id & 31;
        int n = n0 + n4 * 4;
        float4 wv = make_float4(0.f, 0.f, 0.f, 0.f);
        if (n < N) wv = *(const float4*)(W + (size_t)(k0 + kk) * N + n);
        *(float4*)&Ws[kk][n4*4] = wv;
      }
    }
    __syncthreads();
#pragma unroll
    for (int k = 0; k < BK; k++) {
      float4 a0 = *(const float4*)&As[k][my*4];
      float4 a1 = *(const float4*)&As[k][my*4+64];
      float4 b0 = *(const float4*)&Ws[k][nx*4];
      float4 b1 = *(const float4*)&Ws[k][nx*4+64];
      float a[8]  = {a0.x,a0.y,a0.z,a0.w,a1.x,a1.y,a1.z,a1.w};
      float bb[8] = {b0.x,b0.y,b0.z,b0.w,b1.x,b1.y,b1.z,b1.w};
#pragma unroll
      for (int mo = 0; mo < 8; mo++)
#pragma unroll
        for (int nn = 0; nn < 8; nn++)
          acc[mo][nn] = fmaf(a[mo], bb[nn], acc[mo][nn]);
    }
  }

  float bv[8];
#pragma unroll
  for (int nn = 0; nn < 8; nn++) {
    int n = n0 + nx*4 + (nn < 4 ? nn : 60 + nn);
    bv[nn] = (HASBIAS && n < N) ? bias[n] : 0.0f;
  }
#pragma unroll
  for (int mo = 0; mo < 8; mo++) {
    int m = m0 + my*4 + (mo < 4 ? mo : 60 + mo);
#pragma unroll
    for (int h = 0; h < 2; h++) {
      int n = n0 + nx*4 + h*64;
      if (n < N) {
        size_t off = (size_t)m * N + n;
        float v[4];
#pragma unroll
        for (int c = 0; c < 4; c++) v[c] = acc[mo][h*4+c] + bv[h*4+c];
        if (RES) {
          float4 rv = *(const float4*)(C + off);
          v[0]+=rv.x; v[1]+=rv.y; v[2]+=rv.z; v[3]+=rv.w;
        }
        if (ACT == 1) {
#pragma unroll
          for (int c = 0; c < 4; c++) v[c] = geluf(v[c]);
        }
        *(float4*)(C + off) = make_float4(v[0],v[1],v[2],v[3]);
      }
    }
  }
}

// ---------------- layernorm ----
__global__ __launch_bounds__(256) void kln(
    const float* __restrict__ X, const float* __restrict__ gs,
    const float* __restrict__ gb, float* __restrict__ Y)
{
  const int lane = threadIdx.x & 63, wid = threadIdx.x >> 6;
  const int row = blockIdx.x * 4 + wid;
  const float* x = X + (size_t)row * 256;
  float v[4];
#pragma unroll
  for (int c = 0; c < 4; c++) v[c] = x[lane + 64*c];
  float s = v[0]+v[1]+v[2]+v[3];
#pragma unroll
  for (int d = 1; d < 64; d <<= 1) s += __shfl_xor(s, d, 64);
  const float m = s * (1.0f/256.0f);
  float vr = 0.f;
#pragma unroll
  for (int c = 0; c < 4; c++) { float dd = v[c]-m; vr = fmaf(dd, dd, vr); }
#pragma unroll
  for (int d = 1; d < 64; d <<= 1) vr += __shfl_xor(vr, d, 64);
  const float inv = 1.0f / sqrtf(vr * (1.0f/256.0f) + 1e-5f);
  float* y = Y + (size_t)row * 256;
#pragma unroll
  for (int c = 0; c < 4; c++) {
    int col = lane + 64*c;
    y[col] = (v[c]-m) * inv * gs[col] + gb[col];
  }
}

// ---------------- causal attention; QKV packed [8192][768] (q|k|v) ----
__global__ __launch_bounds__(128) void kattn(
    const float* __restrict__ QKV, float* __restrict__ O)
{
  __shared__ float ks[128][64];
  __shared__ float vs[128][64];
  const int h = blockIdx.x, b = blockIdx.y;
  const int tid = threadIdx.x;
  const size_t rbase = (size_t)b * 128;
  {
    const float* kp0 = QKV + (rbase + tid) * 768 + 256 + h * 64;
    const float* vp0 = kp0 + 256;
    const float4* kp = (const float4*)kp0;
    const float4* vp = (const float4*)vp0;
    float4* kd = (float4*)&ks[tid][0];
    float4* vd = (float4*)&vs[tid][0];
#pragma unroll
    for (int c = 0; c < 16; c++) { kd[c] = kp[c]; vd[c] = vp[c]; }
  }
  __syncthreads();
  const int i = tid;
  float qr[64];
  {
    const float4* qp = (const float4*)(QKV + (rbase + i) * 768 + h * 64);
#pragma unroll
    for (int c = 0; c < 16; c++) {
      float4 v = qp[c];
      qr[c*4+0]=v.x; qr[c*4+1]=v.y; qr[c*4+2]=v.z; qr[c*4+3]=v.w;
    }
  }
  float mx = -3.4e38f;
  for (int j = 0; j <= i; j++) {
    float s = 0.f;
#pragma unroll
    for (int d = 0; d < 64; d++) s = fmaf(qr[d], ks[j][d], s);
    mx = fmaxf(mx, s * 0.125f);
  }
  float den = 0.f;
  float o[64];
#pragma unroll
  for (int d = 0; d < 64; d++) o[d] = 0.f;
  for (int j = 0; j <= i; j++) {
    float s = 0.f;
#pragma unroll
    for (int d = 0; d < 64; d++) s = fmaf(qr[d], ks[j][d], s);
    float p = expf(s * 0.125f - mx);
    den += p;
#pragma unroll
    for (int d = 0; d < 64; d++) o[d] = fmaf(p, vs[j][d], o[d]);
  }
  const float inv = 1.0f / den;
  float* op = O + (rbase + i) * 256 + h * 64;
#pragma unroll
  for (int c = 0; c < 16; c++)
    *(float4*)(op + c*4) = make_float4(o[c*4]*inv, o[c*4+1]*inv,
                                       o[c*4+2]*inv, o[c*4+3]*inv);
}

// ---------------------------------------------------------------------------
extern "C" void kernel_launch(void* const* d_in, const int* in_sizes, int n_in,
                              void* d_out, int out_size, void* d_ws, size_t ws_size,
                              hipStream_t stream)
{
  (void)n_in; (void)out_size;
  if (ws_size < (size_t)268435456) return;

  const int o = (in_sizes[1] == 114688) ? 0 : -1;
  const float* x     = (const float*)d_in[0];
  const float* t0w1  = (const float*)d_in[2+o];
  const float* t0b1  = (const float*)d_in[3+o];
  const float* t0w2  = (const float*)d_in[4+o];
  const float* t0b2  = (const float*)d_in[5+o];
  const float* t0dw  = (const float*)d_in[6+o];
  const float* t0db  = (const float*)d_in[7+o];
  const float* t1w1  = (const float*)d_in[8+o];
  const float* t1b1  = (const float*)d_in[9+o];
  const float* t1w2  = (const float*)d_in[10+o];
  const float* t1b2  = (const float*)d_in[11+o];
  const float* t2w1  = (const float*)d_in[12+o];
  const float* t2b1  = (const float*)d_in[13+o];
  const float* t2w2  = (const float*)d_in[14+o];
  const float* t2b2  = (const float*)d_in[15+o];
  const float* qinw  = (const float*)d_in[16+o];
  const float* qinb  = (const float*)d_in[17+o];
  const float* emb   = (const float*)d_in[18+o];
  const float* projw = (const float*)d_in[19+o];
  const float* projb = (const float*)d_in[20+o];
  const float* ln1s  = (const float*)d_in[21+o];
  const float* ln1b  = (const float*)d_in[22+o];
  const float* wq    = (const float*)d_in[23+o];
  const float* bq    = (const float*)d_in[24+o];
  const float* wk    = (const float*)d_in[25+o];
  const float* bk    = (const float*)d_in[26+o];
  const float* wv    = (const float*)d_in[27+o];
  const float* bv    = (const float*)d_in[28+o];
  const float* wo    = (const float*)d_in[29+o];
  const float* bo    = (const float*)d_in[30+o];
  const float* ln2s  = (const float*)d_in[31+o];
  const float* ln2b  = (const float*)d_in[32+o];
  const float* fw1   = (const float*)d_in[33+o];
  const float* fb1   = (const float*)d_in[34+o];
  const float* fw2   = (const float*)d_in[35+o];
  const float* fb2   = (const float*)d_in[36+o];
  const float* hw1   = (const float*)d_in[37+o];
  const float* hb1   = (const float*)d_in[38+o];
  const float* hw2   = (const float*)d_in[39+o];
  const float* hb2   = (const float*)d_in[40+o];
  float* outp = (float*)d_out;
  float* fws  = (float*)d_ws;

  // ---- workspace (67,108,864 floats = 256 MB) ----
  float* fA = fws;                          // [64][256][2048] f32 ping (128 MB)
  float* fB = fws + (size_t)33554432;       // [64][256][2048] f32 pong (128 MB)
  float*  qwT32 = fB;                                   // [4096][256] f32 (4 MB)
  double* q64   = (double*)(fB + (size_t)1048576);      // [8192][256] f64 (16 MB)
  double* cb64  = q64  + (size_t)2097152;               // [1024][256] f64 (2 MB)
  double* cbT64 = cb64 + (size_t)262144;                // [256][1024] f64 (2 MB)
  double* cn64  = cbT64 + (size_t)262144;               // [1024] f64
  double* dot64 = cn64 + 1024;                          // [8192][1024] f64 (64 MB)
  float*  rent  = (float*)(dot64 + (size_t)8388608);    // [8192] f32
  float*  rsq   = rent + 8192;                          // [8192]
  int*    hist  = (int*)(rsq + 8192);                   // [1024]
  float* hbuf = fA;                          // [8192][256]
  float* Nb   = hbuf + (size_t)2097152;      // [8192][256]
  float* QKVb = Nb   + (size_t)2097152;      // [8192][768]
  float* Ob   = QKVb + (size_t)6291456;      // [8192][256]
  float* F1   = fA + (size_t)12582912;       // [8192][1024]
  float* Gb   = fA + (size_t)20971520;       // [8192][512]
  float* qkvw = fA + (size_t)25165824;       // [3][256][768]
  float* qkvb = qkvw + (size_t)589824;       // [3][768]

  // ---- TCN fp32, full batch ----
  dim3 sgrid(8, 2, 64);                      // small convs: BO=128, 256 thr
  dim3 bgrid(8, 1, 64);                      // big convs:   BO=256, 512 thr
  kconv32<7,3,true ,false,true ,128,256><<<sgrid, 256, 0, stream>>>(x, t0w1, t0b1, fA, nullptr);
  kconv32<7,1,true ,false,false,128,256><<<sgrid, 256, 0, stream>>>(x, t0dw, t0db, fB, nullptr);
  kconv32<256,3,false,true ,true ,256,512><<<bgrid, 512, 0, stream>>>(fA, t0w2, t0b2, fB, fB);
  kconv32<256,3,false,false,true ,256,512><<<bgrid, 512, 0, stream>>>(fB, t1w1, t1b1, fA, nullptr);
  kconv32<256,3,false,true ,true ,256,512><<<bgrid, 512, 0, stream>>>(fA, t1w2, t1b2, fB, fB);
  kconv32<256,3,false,false,true ,256,512><<<bgrid, 512, 0, stream>>>(fB, t2w1, t2b1, fA, nullptr);
  kconv32<256,3,false,true ,true ,256,512><<<bgrid, 512, 0, stream>>>(fA, t2w2, t2b2, fB, fB);

  // enc [b][256][2048] (fB) -> patches [b][2048][256] (fA); fB now dead
  ktrans<<<dim3(64, 8, 64), 256, 0, stream>>>(fB, fA, 256, 2048);
  ktrans<<<dim3(128, 8, 1), 256, 0, stream>>>(qinw, qwT32, 256, 4096);

  // ---- sensitive tail in f64 ----
  kgemm64d<float,float,true><<<dim3(128, 2), 256, 0, stream>>>(
      fA, qwT32, qinb, q64, 8192, 256, 4096);
  kgemm64d<float,float,true><<<dim3(16, 2), 256, 0, stream>>>(
      emb, projw, projb, cb64, 1024, 256, 256);
  ktransd64<<<dim3(8, 32, 1), 256, 0, stream>>>(cb64, cbT64, 1024, 256);
  kcnormd<<<256, 256, 0, stream>>>(cb64, cn64);
  kgemm64d<double,double,false><<<dim3(128, 8), 256, 0, stream>>>(
      q64, cbT64, nullptr, dot64, 8192, 1024, 256);
  kzero<<<4, 256, 0, stream>>>(hist, 1024);
  kquantd<<<2048, 256, 0, stream>>>(q64, dot64, cn64, cb64, rent, rsq, hist,
                                    hbuf, outp + 917505);
  kloss<<<1, 256, 0, stream>>>(rent, rsq, hist, outp + 917504);

  // ---- transformer decoder (fp32), fused QKV ----
  kqkvcat<<<2304, 256, 0, stream>>>(wq, wk, wv, bq, bk, bv, qkvw, qkvb);
  for (int l = 0; l < 3; l++) {
    kln<<<2048, 256, 0, stream>>>(hbuf, ln1s + l*256, ln1b + l*256, Nb);
    kgemm<true,false,0><<<dim3(64, 6), 256, 0, stream>>>(Nb, qkvw + (size_t)l*196608, qkvb + l*768, QKVb, 8192, 768, 256);
    kattn<<<dim3(4, 64), 128, 0, stream>>>(QKVb, Ob);
    kgemmN<true,true ,0><<<dim3(128, 2), 256, 0, stream>>>(Ob, wo + (size_t)l*65536, bo + l*256, hbuf, 8192, 256, 256);
    kln<<<2048, 256, 0, stream>>>(hbuf, ln2s + l*256, ln2b + l*256, Nb);
    kgemm<true,false,1><<<dim3(64, 8), 256, 0, stream>>>(Nb, fw1 + (size_t)l*262144, fb1 + l*1024, F1, 8192, 1024, 256);
    kgemmN<true,true ,0><<<dim3(128, 2), 256, 0, stream>>>(F1, fw2 + (size_t)l*262144, fb2 + l*256, hbuf, 8192, 256, 1024);
  }
  // ---- head ----
  kgemm<true,false,1><<<dim3(64, 4), 256, 0, stream>>>(hbuf, hw1, hb1, Gb, 8192, 512, 256);
  kgemm<true,false,0><<<dim3(64, 1), 256, 0, stream>>>(Gb, hw2, hb2, outp, 8192, 112, 512);
}

// Round 21
// 5337.849 us; speedup vs baseline: 2.5208x; 1.0041x over previous
//
#include <hip/hip_runtime.h>
#include <cstddef>

// ---------------------------------------------------------------------------
// VQVAE forward. r20 config (measured 5.36 ms) + one change: kgemm64d gets
// __launch_bounds__(256,1) so the register allocator can keep the f64
// accumulator (64 VGPRs) + operands in architectural VGPRs instead of
// shuffling through AGPRs (r20 counter showed VGPR_Count=64 == acc size).
// Numerics unchanged (scheduling-only). Conv closed at ~737us/dispatch.
// TCN block: out = relu( relu(conv2(relu(conv1+b1))+b2) + res ).
// Workspace 256 MB.
// ---------------------------------------------------------------------------

static __device__ __forceinline__ float geluf(float x) {
  return 0.5f * x * (1.0f + erff(x * 0.70710678118654752440f));
}

// ---------------- fp32 conv: out[b][o][t] over [B][C][T], full batch ----
template<int CIN, int KSIZE, bool FROMX, bool RES, bool RELU, int BO, int NT>
__global__ __launch_bounds__(NT, 2) void kconv32(
    const float* __restrict__ gin, const float* __restrict__ gw,
    const float* __restrict__ gbias, float* __restrict__ gout,
    const float* __restrict__ gres)
{
  constexpr int BT = 256;
  constexpr int PAD = KSIZE - 1;          // causal left pad
  constexpr int KI = (CIN < 16) ? CIN : 16;
  constexpr int JW = KI * KSIZE;
  constexpr int UW = BT + PAD;
  constexpr int UW_S = (KSIZE == 3) ? (UW + 2) : UW;   // stage through halo b128
  constexpr int RS = (UW_S - 1) + (((UW_S - 1) >> 4) << 2) + 1;  // skewed row size
  constexpr int T = 2048;
  constexpr bool SWZ = (CIN >= 16);       // swizzled weight staging (JW%4==0)
  constexpr int WSZ = (KSIZE == 3) ? 20 : 16;
  constexpr int HALF = BO / 2;

  __shared__ float ins[KI][RS];
  __shared__ float wls[JW][BO];

  const int tid = threadIdx.x;
  const int tx = tid & 15, ty = tid >> 4;
  const int t0 = blockIdx.x * BT;
  const int o0 = blockIdx.y * BO;
  const int b  = blockIdx.z;

  const float* inb = gin + (FROMX ? (size_t)b * T * 7 : (size_t)b * 256 * T);

  float acc[8][16];
#pragma unroll
  for (int i = 0; i < 8; i++)
#pragma unroll
    for (int j = 0; j < 16; j++) acc[i][j] = 0.0f;

  for (int i0 = 0; i0 < CIN; i0 += KI) {
    __syncthreads();
    for (int f = tid; f < KI * UW_S; f += NT) {
      int ii = f / UW_S, u = f - ii * UW_S;
      int t = t0 - PAD + u;
      float v = 0.0f;
      if (t >= 0 && t < T) v = FROMX ? inb[t * 7 + (i0 + ii)]
                                     : inb[(size_t)(i0 + ii) * T + t];
      ins[ii][u + ((u >> 4) << 2)] = v;
    }
    if constexpr (SWZ) {
#pragma unroll
      for (int r = 0; r < (JW * BO / 4 + NT - 1) / NT; r++) {
        int f = tid + r * NT;
        int oo = f / (JW / 4);
        int jq = f - oo * (JW / 4);
        int j  = jq * 4;
        const float4 w4 = *(const float4*)&gw[(size_t)(o0 + oo) * (CIN * KSIZE)
                                              + (size_t)i0 * KSIZE + j];
        const int col = (((oo >> 2) ^ jq) << 2) | (oo & 3);
        wls[j + 0][col] = w4.x;
        wls[j + 1][col] = w4.y;
        wls[j + 2][col] = w4.z;
        wls[j + 3][col] = w4.w;
      }
    } else {
      for (int f = tid; f < JW * BO; f += NT) {
        int j = f / BO, oo = f - j * BO;
        wls[j][oo] = gw[(size_t)(o0 + oo) * (CIN * KSIZE) + (size_t)i0 * KSIZE + j];
      }
    }
    __syncthreads();
#pragma unroll
    for (int ii = 0; ii < KI; ii++) {
      float w[WSZ];
      {
        const float* pr = &ins[ii][20 * tx];
        float4 v0 = *(const float4*)(pr + 0);
        float4 v1 = *(const float4*)(pr + 4);
        float4 v2 = *(const float4*)(pr + 8);
        float4 v3 = *(const float4*)(pr + 12);
        w[0]=v0.x; w[1]=v0.y; w[2]=v0.z; w[3]=v0.w;
        w[4]=v1.x; w[5]=v1.y; w[6]=v1.z; w[7]=v1.w;
        w[8]=v2.x; w[9]=v2.y; w[10]=v2.z; w[11]=v2.w;
        w[12]=v3.x; w[13]=v3.y; w[14]=v3.z; w[15]=v3.w;
        if constexpr (KSIZE == 3) {
          float4 v4 = *(const float4*)(pr + 20);
          w[16]=v4.x; w[17]=v4.y; w[18]=v4.z; w[19]=v4.w;
        }
      }
#pragma unroll
      for (int k = 0; k < KSIZE; k++) {
        const int j  = ii * KSIZE + k;
        const int g0 = SWZ ? (ty ^ (j >> 2)) : ty;
        const float* wp = &wls[j][g0 * 4];
        float4 a0 = *(const float4*)wp;
        float4 a1 = *(const float4*)(wp + HALF);
        float a[8] = {a0.x, a0.y, a0.z, a0.w, a1.x, a1.y, a1.z, a1.w};
#pragma unroll
        for (int mo = 0; mo < 8; mo++)
#pragma unroll
          for (int nt = 0; nt < 16; nt++)
            acc[mo][nt] = fmaf(a[mo], w[nt + k], acc[mo][nt]);
      }
    }
  }

  const size_t outbase = (size_t)b * 256 * T;
#pragma unroll
  for (int mo = 0; mo < 8; mo++) {
    const int o = o0 + ty * 4 + (mo < 4 ? mo : (HALF - 4) + mo);
    const float bd = gbias[o];
    const size_t rowb = outbase + (size_t)o * T + t0 + tx * 16;
#pragma unroll
    for (int h = 0; h < 4; h++) {
      const size_t off = rowb + (size_t)h * 4;
      float v[4];
#pragma unroll
      for (int c = 0; c < 4; c++) v[c] = acc[mo][h*4+c] + bd;
      if (RES && RELU) {                       // inner ReLU on h2
#pragma unroll
        for (int c = 0; c < 4; c++) v[c] = fmaxf(v[c], 0.f);
      }
      if (RES) {
        float4 rv = *(const float4*)(gres + off);
        v[0]+=rv.x; v[1]+=rv.y; v[2]+=rv.z; v[3]+=rv.w;
      }
      if (RELU) {
#pragma unroll
        for (int c = 0; c < 4; c++) v[c] = fmaxf(v[c], 0.f);
      }
      *(float4*)(gout + off) = make_float4(v[0], v[1], v[2], v[3]);
    }
  }
}

// ---------------- GEMM, f64 acc/out, BM=64 BN=128, 4x8 micro-tile ----
// launch_bounds(256,1): raise VGPR ceiling so the 64-reg f64 accumulator
// stays in architectural VGPRs (r20: VGPR_Count=64 => AGPR shuffling).
template<typename TA, typename TW, bool HASBIAS>
__global__ __launch_bounds__(256, 1) void kgemm64d(
    const TA* __restrict__ A, const TW* __restrict__ W,
    const float* __restrict__ bias, double* __restrict__ C,
    int M, int N, int K)
{
  constexpr int BM = 64, BN = 128, BK = 16;
  __shared__ double As[BK][BM + 2];
  __shared__ double Ws[BK][BN + 2];
  const int tid = threadIdx.x;
  const int nx = tid & 15, my = tid >> 4;
  const int m0 = blockIdx.x * BM, n0 = blockIdx.y * BN;

  double acc[4][8];
#pragma unroll
  for (int i = 0; i < 4; i++)
#pragma unroll
    for (int j = 0; j < 8; j++) acc[i][j] = 0.0;

  for (int k0 = 0; k0 < K; k0 += BK) {
    __syncthreads();
    {
      int mm = tid >> 2, k4 = (tid & 3) * 4;
      const TA* ap = A + (size_t)(m0 + mm) * K + k0 + k4;
#pragma unroll
      for (int j = 0; j < 4; j++) As[k4 + j][mm] = (double)ap[j];
    }
#pragma unroll
    for (int r = 0; r < 8; r++) {
      int f = tid + r * 256;
      int kk = f >> 7, n = f & 127;
      Ws[kk][n] = (double)W[(size_t)(k0 + kk) * N + n0 + n];
    }
    __syncthreads();
#pragma unroll
    for (int k = 0; k < BK; k++) {
      double a[4], b[8];
#pragma unroll
      for (int i = 0; i < 4; i++) a[i] = As[k][my * 4 + i];
#pragma unroll
      for (int j = 0; j < 4; j++) { b[j] = Ws[k][nx * 4 + j]; b[4 + j] = Ws[k][nx * 4 + 64 + j]; }
#pragma unroll
      for (int i = 0; i < 4; i++)
#pragma unroll
        for (int j = 0; j < 8; j++)
          acc[i][j] = fma(a[i], b[j], acc[i][j]);
    }
  }

#pragma unroll
  for (int i = 0; i < 4; i++) {
    int m = m0 + my * 4 + i;
#pragma unroll
    for (int j = 0; j < 8; j++) {
      int n = n0 + nx * 4 + (j < 4 ? j : 60 + j);
      double v = acc[i][j];
      if (HASBIAS) v += (double)bias[n];
      C[(size_t)m * N + n] = v;
    }
  }
}

// ---------------- fp32 GEMM, BM=64 BN=128 (full-grid N=256 decoder GEMMs) ----
template<bool HASBIAS, bool RES, int ACT>
__global__ __launch_bounds__(256) void kgemmN(
    const float* __restrict__ A, const float* __restrict__ W,
    const float* __restrict__ bias, float* __restrict__ C,
    int M, int N, int K)
{
  constexpr int BM = 64, BN = 128, BK = 16;
  __shared__ float As[BK][BM + 4];
  __shared__ float Ws[BK][BN + 4];
  const int tid = threadIdx.x;
  const int nx = tid & 15, my = tid >> 4;
  const int m0 = blockIdx.x * BM, n0 = blockIdx.y * BN;

  float acc[4][8];
#pragma unroll
  for (int i = 0; i < 4; i++)
#pragma unroll
    for (int j = 0; j < 8; j++) acc[i][j] = 0.0f;

  for (int k0 = 0; k0 < K; k0 += BK) {
    __syncthreads();
    {
      int mm = tid >> 2, k4 = (tid & 3) * 4;
      float4 v = *(const float4*)(A + (size_t)(m0 + mm) * K + k0 + k4);
      As[k4+0][mm] = v.x; As[k4+1][mm] = v.y;
      As[k4+2][mm] = v.z; As[k4+3][mm] = v.w;
    }
#pragma unroll
    for (int rep = 0; rep < 2; rep++) {
      int id = tid + rep * 256;
      int kk = id >> 5, n4 = id & 31;
      float4 wv = *(const float4*)(W + (size_t)(k0 + kk) * N + n0 + n4 * 4);
      *(float4*)&Ws[kk][n4*4] = wv;
    }
    __syncthreads();
#pragma unroll
    for (int k = 0; k < BK; k++) {
      float4 af = *(const float4*)&As[k][my*4];
      float4 b0 = *(const float4*)&Ws[k][nx*4];
      float4 b1 = *(const float4*)&Ws[k][nx*4+64];
      float a[4]  = {af.x, af.y, af.z, af.w};
      float bb[8] = {b0.x,b0.y,b0.z,b0.w,b1.x,b1.y,b1.z,b1.w};
#pragma unroll
      for (int i = 0; i < 4; i++)
#pragma unroll
        for (int j = 0; j < 8; j++)
          acc[i][j] = fmaf(a[i], bb[j], acc[i][j]);
    }
  }

  float bv[8];
#pragma unroll
  for (int j = 0; j < 8; j++) {
    int n = n0 + nx*4 + (j < 4 ? j : 60 + j);
    bv[j] = HASBIAS ? bias[n] : 0.0f;
  }
#pragma unroll
  for (int i = 0; i < 4; i++) {
    int m = m0 + my * 4 + i;
#pragma unroll
    for (int h = 0; h < 2; h++) {
      int n = n0 + nx*4 + h*64;
      size_t off = (size_t)m * N + n;
      float v[4];
#pragma unroll
      for (int c = 0; c < 4; c++) v[c] = acc[i][h*4+c] + bv[h*4+c];
      if (RES) {
        float4 rv = *(const float4*)(C + off);
        v[0]+=rv.x; v[1]+=rv.y; v[2]+=rv.z; v[3]+=rv.w;
      }
      if (ACT == 1) {
#pragma unroll
        for (int c = 0; c < 4; c++) v[c] = geluf(v[c]);
      }
      *(float4*)(C + off) = make_float4(v[0],v[1],v[2],v[3]);
    }
  }
}

// ---------------- f32 transpose: out[Cc][R] = in[R][Cc], batched ----
__global__ __launch_bounds__(256) void ktrans(
    const float* __restrict__ in, float* __restrict__ out, int R, int Cc)
{
  __shared__ float tile[32][33];
  const int tx = threadIdx.x & 31, ty = threadIdx.x >> 5;
  const int c0 = blockIdx.x * 32, r0 = blockIdx.y * 32;
  const size_t zoff = (size_t)blockIdx.z * (size_t)R * Cc;
  const float* ib = in + zoff;
  float* ob = out + zoff;
#pragma unroll
  for (int s = 0; s < 32; s += 8)
    tile[ty + s][tx] = ib[(size_t)(r0 + ty + s) * Cc + c0 + tx];
  __syncthreads();
#pragma unroll
  for (int s = 0; s < 32; s += 8)
    ob[(size_t)(c0 + ty + s) * R + r0 + tx] = tile[tx][ty + s];
}

// ---------------- f64 transpose (codebook) ----
__global__ __launch_bounds__(256) void ktransd64(
    const double* __restrict__ in, double* __restrict__ out, int R, int Cc)
{
  __shared__ double tile[32][33];
  const int tx = threadIdx.x & 31, ty = threadIdx.x >> 5;
  const int c0 = blockIdx.x * 32, r0 = blockIdx.y * 32;
#pragma unroll
  for (int s = 0; s < 32; s += 8)
    tile[ty + s][tx] = in[(size_t)(r0 + ty + s) * Cc + c0 + tx];
  __syncthreads();
#pragma unroll
  for (int s = 0; s < 32; s += 8)
    out[(size_t)(c0 + ty + s) * R + r0 + tx] = tile[tx][ty + s];
}

// ---------------- codebook row norms f64 ----
__global__ __launch_bounds__(256) void kcnormd(const double* __restrict__ cb,
                                               double* __restrict__ cn)
{
  const int lane = threadIdx.x & 63, wid = threadIdx.x >> 6;
  const int row = blockIdx.x * 4 + wid;
  const double* x = cb + (size_t)row * 256;
  double s = 0.0;
#pragma unroll
  for (int c = 0; c < 4; c++) { double v = x[lane + 64 * c]; s = fma(v, v, s); }
#pragma unroll
  for (int d = 1; d < 64; d <<= 1) s += __shfl_xor(s, d, 64);
  if (lane == 0) cn[row] = s;
}

// ---------------- zero ints ----
__global__ __launch_bounds__(256) void kzero(int* __restrict__ p, int n)
{
  int i = blockIdx.x * 256 + threadIdx.x;
  if (i < n) p[i] = 0;
}

// ---------------- concat QKV weights/biases ----
__global__ __launch_bounds__(256) void kqkvcat(
    const float* __restrict__ wq, const float* __restrict__ wk,
    const float* __restrict__ wv, const float* __restrict__ bq,
    const float* __restrict__ bk, const float* __restrict__ bv,
    float* __restrict__ qkvw, float* __restrict__ qkvb)
{
  int idx = blockIdx.x * 256 + threadIdx.x;
  if (idx < 589824) {
    int l = idx / 196608;
    int rem = idx - l * 196608;
    int k = rem / 768, n = rem - k * 768;
    const float* src = (n < 256) ? wq : (n < 512) ? wk : wv;
    qkvw[idx] = src[(size_t)l * 65536 + k * 256 + (n & 255)];
  }
  if (idx < 2304) {
    int l = idx / 768, n = idx - l * 768;
    const float* sb = (n < 256) ? bq : (n < 512) ? bk : bv;
    qkvb[idx] = sb[l * 256 + (n & 255)];
  }
}

// ---------------- VQ per-row, all-f64 logits/argmax ----
__global__ __launch_bounds__(256) void kquantd(
    const double* __restrict__ q, const double* __restrict__ dot,
    const double* __restrict__ cn, const double* __restrict__ cb,
    float* __restrict__ rent, float* __restrict__ rsq,
    int* __restrict__ hist, float* __restrict__ h0, float* __restrict__ idxf)
{
  const int lane = threadIdx.x & 63, wid = threadIdx.x >> 6;
  const int n = blockIdx.x * 4 + wid;
  const double* qr = q + (size_t)n * 256;
  double qv[4];
#pragma unroll
  for (int c = 0; c < 4; c++) qv[c] = qr[lane + 64 * c];
  double qn = 0.0;
#pragma unroll
  for (int c = 0; c < 4; c++) qn = fma(qv[c], qv[c], qn);
#pragma unroll
  for (int d = 1; d < 64; d <<= 1) qn += __shfl_xor(qn, d, 64);

  const double* dr = dot + (size_t)n * 1024;
  double lg[16];
  double mx = -1.0e300; int bi = 0;
#pragma unroll
  for (int c = 0; c < 16; c++) {
    int j = lane + 64 * c;
    double l = -(qn + cn[j] - 2.0 * dr[j]);   // logits = -d (ETEMP=1)
    lg[c] = l;
    if (l > mx) { mx = l; bi = j; }
  }
#pragma unroll
  for (int d = 1; d < 64; d <<= 1) {
    double om = __shfl_xor(mx, d, 64);
    int    ob = __shfl_xor(bi, d, 64);
    if (om > mx || (om == mx && ob < bi)) { mx = om; bi = ob; }
  }
  float ssum = 0.f;
  float ef[16];
#pragma unroll
  for (int c = 0; c < 16; c++) { ef[c] = expf((float)(lg[c] - mx)); ssum += ef[c]; }
#pragma unroll
  for (int d = 1; d < 64; d <<= 1) ssum += __shfl_xor(ssum, d, 64);
  const float invs = 1.0f / ssum;
  float ent = 0.f;
#pragma unroll
  for (int c = 0; c < 16; c++) {
    float p = ef[c] * invs;
    ent -= p * logf(p + 1e-5f);
  }
#pragma unroll
  for (int d = 1; d < 64; d <<= 1) ent += __shfl_xor(ent, d, 64);

  const double* cbr = cb + (size_t)bi * 256;
  double sq = 0.0;
#pragma unroll
  for (int c = 0; c < 4; c++) {
    int col = lane + 64 * c;
    double z = cbr[col];
    double df = z - qv[c];
    sq = fma(df, df, sq);
    h0[(size_t)n * 256 + col] = (float)z;     // straight-through forward value
  }
#pragma unroll
  for (int d = 1; d < 64; d <<= 1) sq += __shfl_xor(sq, d, 64);

  if (lane == 0) {
    rent[n] = ent;
    rsq[n]  = (float)sq;
    atomicAdd(&hist[bi], 1);
    idxf[n] = (float)bi;
  }
}

// ---------------- final scalar loss ----
__global__ __launch_bounds__(256) void kloss(
    const float* __restrict__ rent, const float* __restrict__ rsq,
    const int* __restrict__ hist, float* __restrict__ outp)
{
  __shared__ float r0[256], r1[256], r2[256];
  const int tid = threadIdx.x;
  float se = 0.f, sq = 0.f, te = 0.f;
  for (int i = tid; i < 8192; i += 256) { se += rent[i]; sq += rsq[i]; }
  for (int j = tid; j < 1024; j += 256) {
    float a = (float)hist[j] * (1.0f / 8192.0f) + 1e-5f;
    te -= a * logf(a);
  }
  r0[tid] = se; r1[tid] = sq; r2[tid] = te;
  __syncthreads();
  for (int s = 128; s > 0; s >>= 1) {
    if (tid < s) { r0[tid] += r0[tid+s]; r1[tid] += r1[tid+s]; r2[tid] += r2[tid+s]; }
    __syncthreads();
  }
  if (tid == 0) {
    const float ln1024 = 6.9314718055994531f;
    float soft_ent  = r0[0] * (1.0f / 8192.0f);
    float soft_loss = 0.1f * (1.0f - soft_ent / ln1024);
    float vq        = 1.25f * (r1[0] / (8192.0f * 256.0f));
    float tok       = 0.1f * (1.0f - r2[0] / ln1024);
    outp[0] = vq + soft_loss + tok;
  }
}

// ---------------- generic fp32 GEMM (BM=128; QKV/FFN1/head) ----
template<bool HASBIAS, bool RES, int ACT>
__global__ __launch_bounds__(256) void kgemm(
    const float* __restrict__ A, const float* __restrict__ W,
    const float* __restrict__ bias, float* __restrict__ C,
    int M, int N, int K)
{
  constexpr int BM = 128, BN = 128, BK = 16;
  __shared__ float As[BK][BM + 4];
  __shared__ float Ws[BK][BN + 4];
  const int tid = threadIdx.x;
  const int nx = tid & 15, my = tid >> 4;
  const int m0 = blockIdx.x * BM, n0 = blockIdx.y * BN;

  float acc[8][8];
#pragma unroll
  for (int i = 0; i < 8; i++)
#pragma unroll
    for (int j = 0; j < 8; j++) acc[i][j] = 0.0f;

  for (int k0 = 0; k0 < K; k0 += BK) {
    __syncthreads();
#pragma unroll
    for (int rep = 0; rep < 2; rep++) {
      int id = tid + rep * 256;
      {
        int r = id >> 2, c4 = id & 3;
        float4 v = *(const float4*)(A + (size_t)(m0 + r) * K + k0 + c4 * 4);
        As[c4*4+0][r] = v.x; As[c4*4+1][r] = v.y;
        As[c4*4+2][r] = v.z; As[c4*4+3][r] = v.w;
      }
      {
        int kk = id >> 5, n4 = id & 31;
        int n = n0 + n4 * 4;
        float4 wv = make_float4(0.f, 0.f, 0.f, 0.f);
        if (n < N) wv = *(const float4*)(W + (size_t)(k0 + kk) * N + n);
        *(float4*)&Ws[kk][n4*4] = wv;
      }
    }
    __syncthreads();
#pragma unroll
    for (int k = 0; k < BK; k++) {
      float4 a0 = *(const float4*)&As[k][my*4];
      float4 a1 = *(const float4*)&As[k][my*4+64];
      float4 b0 = *(const float4*)&Ws[k][nx*4];
      float4 b1 = *(const float4*)&Ws[k][nx*4+64];
      float a[8]  = {a0.x,a0.y,a0.z,a0.w,a1.x,a1.y,a1.z,a1.w};
      float bb[8] = {b0.x,b0.y,b0.z,b0.w,b1.x,b1.y,b1.z,b1.w};
#pragma unroll
      for (int mo = 0; mo < 8; mo++)
#pragma unroll
        for (int nn = 0; nn < 8; nn++)
          acc[mo][nn] = fmaf(a[mo], bb[nn], acc[mo][nn]);
    }
  }

  float bv[8];
#pragma unroll
  for (int nn = 0; nn < 8; nn++) {
    int n = n0 + nx*4 + (nn < 4 ? nn : 60 + nn);
    bv[nn] = (HASBIAS && n < N) ? bias[n] : 0.0f;
  }
#pragma unroll
  for (int mo = 0; mo < 8; mo++) {
    int m = m0 + my*4 + (mo < 4 ? mo : 60 + mo);
#pragma unroll
    for (int h = 0; h < 2; h++) {
      int n = n0 + nx*4 + h*64;
      if (n < N) {
        size_t off = (size_t)m * N + n;
        float v[4];
#pragma unroll
        for (int c = 0; c < 4; c++) v[c] = acc[mo][h*4+c] + bv[h*4+c];
        if (RES) {
          float4 rv = *(const float4*)(C + off);
          v[0]+=rv.x; v[1]+=rv.y; v[2]+=rv.z; v[3]+=rv.w;
        }
        if (ACT == 1) {
#pragma unroll
          for (int c = 0; c < 4; c++) v[c] = geluf(v[c]);
        }
        *(float4*)(C + off) = make_float4(v[0],v[1],v[2],v[3]);
      }
    }
  }
}

// ---------------- layernorm ----
__global__ __launch_bounds__(256) void kln(
    const float* __restrict__ X, const float* __restrict__ gs,
    const float* __restrict__ gb, float* __restrict__ Y)
{
  const int lane = threadIdx.x & 63, wid = threadIdx.x >> 6;
  const int row = blockIdx.x * 4 + wid;
  const float* x = X + (size_t)row * 256;
  float v[4];
#pragma unroll
  for (int c = 0; c < 4; c++) v[c] = x[lane + 64*c];
  float s = v[0]+v[1]+v[2]+v[3];
#pragma unroll
  for (int d = 1; d < 64; d <<= 1) s += __shfl_xor(s, d, 64);
  const float m = s * (1.0f/256.0f);
  float vr = 0.f;
#pragma unroll
  for (int c = 0; c < 4; c++) { float dd = v[c]-m; vr = fmaf(dd, dd, vr); }
#pragma unroll
  for (int d = 1; d < 64; d <<= 1) vr += __shfl_xor(vr, d, 64);
  const float inv = 1.0f / sqrtf(vr * (1.0f/256.0f) + 1e-5f);
  float* y = Y + (size_t)row * 256;
#pragma unroll
  for (int c = 0; c < 4; c++) {
    int col = lane + 64*c;
    y[col] = (v[c]-m) * inv * gs[col] + gb[col];
  }
}

// ---------------- causal attention; QKV packed [8192][768] (q|k|v) ----
__global__ __launch_bounds__(128) void kattn(
    const float* __restrict__ QKV, float* __restrict__ O)
{
  __shared__ float ks[128][64];
  __shared__ float vs[128][64];
  const int h = blockIdx.x, b = blockIdx.y;
  const int tid = threadIdx.x;
  const size_t rbase = (size_t)b * 128;
  {
    const float* kp0 = QKV + (rbase + tid) * 768 + 256 + h * 64;
    const float* vp0 = kp0 + 256;
    const float4* kp = (const float4*)kp0;
    const float4* vp = (const float4*)vp0;
    float4* kd = (float4*)&ks[tid][0];
    float4* vd = (float4*)&vs[tid][0];
#pragma unroll
    for (int c = 0; c < 16; c++) { kd[c] = kp[c]; vd[c] = vp[c]; }
  }
  __syncthreads();
  const int i = tid;
  float qr[64];
  {
    const float4* qp = (const float4*)(QKV + (rbase + i) * 768 + h * 64);
#pragma unroll
    for (int c = 0; c < 16; c++) {
      float4 v = qp[c];
      qr[c*4+0]=v.x; qr[c*4+1]=v.y; qr[c*4+2]=v.z; qr[c*4+3]=v.w;
    }
  }
  float mx = -3.4e38f;
  for (int j = 0; j <= i; j++) {
    float s = 0.f;
#pragma unroll
    for (int d = 0; d < 64; d++) s = fmaf(qr[d], ks[j][d], s);
    mx = fmaxf(mx, s * 0.125f);
  }
  float den = 0.f;
  float o[64];
#pragma unroll
  for (int d = 0; d < 64; d++) o[d] = 0.f;
  for (int j = 0; j <= i; j++) {
    float s = 0.f;
#pragma unroll
    for (int d = 0; d < 64; d++) s = fmaf(qr[d], ks[j][d], s);
    float p = expf(s * 0.125f - mx);
    den += p;
#pragma unroll
    for (int d = 0; d < 64; d++) o[d] = fmaf(p, vs[j][d], o[d]);
  }
  const float inv = 1.0f / den;
  float* op = O + (rbase + i) * 256 + h * 64;
#pragma unroll
  for (int c = 0; c < 16; c++)
    *(float4*)(op + c*4) = make_float4(o[c*4]*inv, o[c*4+1]*inv,
                                       o[c*4+2]*inv, o[c*4+3]*inv);
}

// ---------------------------------------------------------------------------
extern "C" void kernel_launch(void* const* d_in, const int* in_sizes, int n_in,
                              void* d_out, int out_size, void* d_ws, size_t ws_size,
                              hipStream_t stream)
{
  (void)n_in; (void)out_size;
  if (ws_size < (size_t)268435456) return;

  const int o = (in_sizes[1] == 114688) ? 0 : -1;
  const float* x     = (const float*)d_in[0];
  const float* t0w1  = (const float*)d_in[2+o];
  const float* t0b1  = (const float*)d_in[3+o];
  const float* t0w2  = (const float*)d_in[4+o];
  const float* t0b2  = (const float*)d_in[5+o];
  const float* t0dw  = (const float*)d_in[6+o];
  const float* t0db  = (const float*)d_in[7+o];
  const float* t1w1  = (const float*)d_in[8+o];
  const float* t1b1  = (const float*)d_in[9+o];
  const float* t1w2  = (const float*)d_in[10+o];
  const float* t1b2  = (const float*)d_in[11+o];
  const float* t2w1  = (const float*)d_in[12+o];
  const float* t2b1  = (const float*)d_in[13+o];
  const float* t2w2  = (const float*)d_in[14+o];
  const float* t2b2  = (const float*)d_in[15+o];
  const float* qinw  = (const float*)d_in[16+o];
  const float* qinb  = (const float*)d_in[17+o];
  const float* emb   = (const float*)d_in[18+o];
  const float* projw = (const float*)d_in[19+o];
  const float* projb = (const float*)d_in[20+o];
  const float* ln1s  = (const float*)d_in[21+o];
  const float* ln1b  = (const float*)d_in[22+o];
  const float* wq    = (const float*)d_in[23+o];
  const float* bq    = (const float*)d_in[24+o];
  const float* wk    = (const float*)d_in[25+o];
  const float* bk    = (const float*)d_in[26+o];
  const float* wv    = (const float*)d_in[27+o];
  const float* bv    = (const float*)d_in[28+o];
  const float* wo    = (const float*)d_in[29+o];
  const float* bo    = (const float*)d_in[30+o];
  const float* ln2s  = (const float*)d_in[31+o];
  const float* ln2b  = (const float*)d_in[32+o];
  const float* fw1   = (const float*)d_in[33+o];
  const float* fb1   = (const float*)d_in[34+o];
  const float* fw2   = (const float*)d_in[35+o];
  const float* fb2   = (const float*)d_in[36+o];
  const float* hw1   = (const float*)d_in[37+o];
  const float* hb1   = (const float*)d_in[38+o];
  const float* hw2   = (const float*)d_in[39+o];
  const float* hb2   = (const float*)d_in[40+o];
  float* outp = (float*)d_out;
  float* fws  = (float*)d_ws;

  // ---- workspace (67,108,864 floats = 256 MB) ----
  float* fA = fws;                          // [64][256][2048] f32 ping (128 MB)
  float* fB = fws + (size_t)33554432;       // [64][256][2048] f32 pong (128 MB)
  float*  qwT32 = fB;                                   // [4096][256] f32 (4 MB)
  double* q64   = (double*)(fB + (size_t)1048576);      // [8192][256] f64 (16 MB)
  double* cb64  = q64  + (size_t)2097152;               // [1024][256] f64 (2 MB)
  double* cbT64 = cb64 + (size_t)262144;                // [256][1024] f64 (2 MB)
  double* cn64  = cbT64 + (size_t)262144;               // [1024] f64
  double* dot64 = cn64 + 1024;                          // [8192][1024] f64 (64 MB)
  float*  rent  = (float*)(dot64 + (size_t)8388608);    // [8192] f32
  float*  rsq   = rent + 8192;                          // [8192]
  int*    hist  = (int*)(rsq + 8192);                   // [1024]
  float* hbuf = fA;                          // [8192][256]
  float* Nb   = hbuf + (size_t)2097152;      // [8192][256]
  float* QKVb = Nb   + (size_t)2097152;      // [8192][768]
  float* Ob   = QKVb + (size_t)6291456;      // [8192][256]
  float* F1   = fA + (size_t)12582912;       // [8192][1024]
  float* Gb   = fA + (size_t)20971520;       // [8192][512]
  float* qkvw = fA + (size_t)25165824;       // [3][256][768]
  float* qkvb = qkvw + (size_t)589824;       // [3][768]

  // ---- TCN fp32, full batch ----
  dim3 sgrid(8, 2, 64);                      // small convs: BO=128, 256 thr
  dim3 bgrid(8, 1, 64);                      // big convs:   BO=256, 512 thr
  kconv32<7,3,true ,false,true ,128,256><<<sgrid, 256, 0, stream>>>(x, t0w1, t0b1, fA, nullptr);
  kconv32<7,1,true ,false,false,128,256><<<sgrid, 256, 0, stream>>>(x, t0dw, t0db, fB, nullptr);
  kconv32<256,3,false,true ,true ,256,512><<<bgrid, 512, 0, stream>>>(fA, t0w2, t0b2, fB, fB);
  kconv32<256,3,false,false,true ,256,512><<<bgrid, 512, 0, stream>>>(fB, t1w1, t1b1, fA, nullptr);
  kconv32<256,3,false,true ,true ,256,512><<<bgrid, 512, 0, stream>>>(fA, t1w2, t1b2, fB, fB);
  kconv32<256,3,false,false,true ,256,512><<<bgrid, 512, 0, stream>>>(fB, t2w1, t2b1, fA, nullptr);
  kconv32<256,3,false,true ,true ,256,512><<<bgrid, 512, 0, stream>>>(fA, t2w2, t2b2, fB, fB);

  // enc [b][256][2048] (fB) -> patches [b][2048][256] (fA); fB now dead
  ktrans<<<dim3(64, 8, 64), 256, 0, stream>>>(fB, fA, 256, 2048);
  ktrans<<<dim3(128, 8, 1), 256, 0, stream>>>(qinw, qwT32, 256, 4096);

  // ---- sensitive tail in f64 ----
  kgemm64d<float,float,true><<<dim3(128, 2), 256, 0, stream>>>(
      fA, qwT32, qinb, q64, 8192, 256, 4096);
  kgemm64d<float,float,true><<<dim3(16, 2), 256, 0, stream>>>(
      emb, projw, projb, cb64, 1024, 256, 256);
  ktransd64<<<dim3(8, 32, 1), 256, 0, stream>>>(cb64, cbT64, 1024, 256);
  kcnormd<<<256, 256, 0, stream>>>(cb64, cn64);
  kgemm64d<double,double,false><<<dim3(128, 8), 256, 0, stream>>>(
      q64, cbT64, nullptr, dot64, 8192, 1024, 256);
  kzero<<<4, 256, 0, stream>>>(hist, 1024);
  kquantd<<<2048, 256, 0, stream>>>(q64, dot64, cn64, cb64, rent, rsq, hist,
                                    hbuf, outp + 917505);
  kloss<<<1, 256, 0, stream>>>(rent, rsq, hist, outp + 917504);

  // ---- transformer decoder (fp32), fused QKV ----
  kqkvcat<<<2304, 256, 0, stream>>>(wq, wk, wv, bq, bk, bv, qkvw, qkvb);
  for (int l = 0; l < 3; l++) {
    kln<<<2048, 256, 0, stream>>>(hbuf, ln1s + l*256, ln1b + l*256, Nb);
    kgemm<true,false,0><<<dim3(64, 6), 256, 0, stream>>>(Nb, qkvw + (size_t)l*196608, qkvb + l*768, QKVb, 8192, 768, 256);
    kattn<<<dim3(4, 64), 128, 0, stream>>>(QKVb, Ob);
    kgemmN<true,true ,0><<<dim3(128, 2), 256, 0, stream>>>(Ob, wo + (size_t)l*65536, bo + l*256, hbuf, 8192, 256, 256);
    kln<<<2048, 256, 0, stream>>>(hbuf, ln2s + l*256, ln2b + l*256, Nb);
    kgemm<true,false,1><<<dim3(64, 8), 256, 0, stream>>>(Nb, fw1 + (size_t)l*262144, fb1 + l*1024, F1, 8192, 1024, 256);
    kgemmN<true,true ,0><<<dim3(128, 2), 256, 0, stream>>>(F1, fw2 + (size_t)l*262144, fb2 + l*256, hbuf, 8192, 256, 1024);
  }
  // ---- head ----
  kgemm<true,false,1><<<dim3(64, 4), 256, 0, stream>>>(hbuf, hw1, hb1, Gb, 8192, 512, 256);
  kgemm<true,false,0><<<dim3(64, 1), 256, 0, stream>>>(Gb, hw2, hb2, outp, 8192, 112, 512);
}